// Round 1
// baseline (10357.995 us; speedup 1.0000x reference)
//
#include <hip/hip_runtime.h>

typedef unsigned short u16;
typedef unsigned int   u32;
typedef unsigned long long u64;

typedef short bf16x8 __attribute__((ext_vector_type(8)));
typedef float f32x4  __attribute__((ext_vector_type(4)));

#define A_SYN  0.90483741803595957f   // exp(-0.5/5)
#define A_VM   0.95122942450071400f   // exp(-0.5/10)
#define BETA   0.04877057549928600f   // 1 - A_VM
#define C_RATE 0.09754115099857200f   // (1/DT)*(1-alpha_out) = 2*BETA
#define R_H    0.04419417382415922f   // 1*1*10/5 * sqrt(1/2048)
#define R_IN   4.41941738241592200f   // 10*1*10 * sqrt(1/512)
#define R_OUT  2.20970869120796080f   // 100 * sqrt(1/2048)

__device__ __forceinline__ u16 f2b(float f){
  u32 x = __float_as_uint(f);
  return (u16)((x + 0x7FFFu + ((x >> 16) & 1u)) >> 16);   // RNE f32->bf16
}
__device__ __forceinline__ float b2f(u16 u){ return __uint_as_float(((u32)u) << 16); }

// ---------------- prep: row sums of x -> sbeta[m]; convert x to bf16 ----------------
__global__ __launch_bounds__(256) void prep_x(const float* __restrict__ x,
                                              u16* __restrict__ xb,
                                              float* __restrict__ sbeta){
  const int m = blockIdx.x;          // 16384 rows
  const int tid = threadIdx.x;       // 256 threads, 4 floats each
  const float4 xv = ((const float4*)(x + (size_t)m * 1024))[tid];
  float s = xv.x + xv.y + xv.z + xv.w;
  #pragma unroll
  for (int off = 32; off > 0; off >>= 1) s += __shfl_down(s, off, 64);
  __shared__ float ps[4];
  if ((tid & 63) == 0) ps[tid >> 6] = s;
  __syncthreads();
  float tot = ps[0] + ps[1] + ps[2] + ps[3];
  float sc = fminf(30.0f / (tot + 1.0f), 10.0f) * (R_IN * BETA);
  if (tid == 0) sbeta[m] = sc;
  ushort4 o; o.x = f2b(xv.x); o.y = f2b(xv.y); o.z = f2b(xv.z); o.w = f2b(xv.w);
  ((ushort4*)(xb + (size_t)m * 1024))[tid] = o;
}

// ---------------- detect bool layout: int32 words (0/1) vs packed bytes ----------------
__global__ void detect_layout(const u32* __restrict__ khw, u32* __restrict__ flag){
  u32 bad = 0;
  #pragma unroll
  for (int i = 0; i < 4; ++i){ u32 v = khw[threadIdx.x + i * 256]; bad |= (v > 1u) ? 1u : 0u; }
  if (bad) *flag = 1u;   // idempotent, deterministic
}

// ---------------- prep: kernel_in -> Bt[n][k] bf16 (transposed) ----------------
__global__ __launch_bounds__(256) void prep_bt(const int* __restrict__ ki,
                                               const u32* __restrict__ flag,
                                               u16* __restrict__ Bt){
  __shared__ u16 tile[64][65];
  const int k0 = blockIdx.x * 64, n0 = blockIdx.y * 64;
  const int tr = threadIdx.x >> 6, tc = threadIdx.x & 63;
  const bool bm = (*flag) != 0;
  const unsigned char* kib = (const unsigned char*)ki;
  #pragma unroll 4
  for (int r = 0; r < 16; ++r){
    int row = r * 4 + tr;
    size_t idx = (size_t)(k0 + row) * 4096 + (n0 + tc);
    int v = bm ? (int)kib[idx] : ki[idx];
    tile[row][tc] = v ? (u16)0x3F80 : (u16)0;
  }
  __syncthreads();
  #pragma unroll 4
  for (int r = 0; r < 16; ++r){
    int row = r * 4 + tr;   // n-local
    Bt[(size_t)(n0 + row) * 1024 + (k0 + tc)] = tile[tc][row];
  }
}

// ---------------- prep: kernel_h -> khT bit-packed [w][n], bit j = kh[w*64+j][n] ----------------
__global__ __launch_bounds__(256) void prep_kh(const int* __restrict__ kh,
                                               const u32* __restrict__ flag,
                                               u64* __restrict__ khT){
  const int n = blockIdx.x * 256 + threadIdx.x;
  const int w = blockIdx.y;
  const bool bm = (*flag) != 0;
  const unsigned char* khb = (const unsigned char*)kh;
  u64 bits = 0;
  #pragma unroll 8
  for (int j = 0; j < 64; ++j){
    size_t idx = (size_t)(w * 64 + j) * 4096 + n;
    int v = bm ? (int)khb[idx] : kh[idx];
    bits |= (u64)(v & 1) << j;
  }
  khT[(size_t)w * 4096 + n] = bits;
}

// ---------------- bf16 GEMM: i_in_beta[m][n] = bf16(sbeta[m] * sum_k xb[m][k]*Bt[n][k]) ----------------
__global__ __launch_bounds__(256) void gemm_iin(const u16* __restrict__ A,
                                                const u16* __restrict__ Bm,
                                                const float* __restrict__ sbeta,
                                                u16* __restrict__ C){
  __shared__ u16 As[128 * 32];
  __shared__ u16 Bs[128 * 32];
  const int tid = threadIdx.x;
  const int lane = tid & 63, w = tid >> 6;
  const int wm = w >> 1, wn = w & 1;
  const int m0 = blockIdx.x * 128, n0 = blockIdx.y * 128;
  const int l15 = lane & 15, lq = lane >> 4;
  const int K = 1024;

  f32x4 acc[4][4];
  #pragma unroll
  for (int i = 0; i < 4; ++i)
    #pragma unroll
    for (int j = 0; j < 4; ++j) acc[i][j] = (f32x4){0.f, 0.f, 0.f, 0.f};

  const u16* ag = A  + (size_t)(m0 + (tid >> 2)) * K + (tid & 3) * 8;
  const u16* bg = Bm + (size_t)(n0 + (tid >> 2)) * K + (tid & 3) * 8;

  for (int kt = 0; kt < 32; ++kt){
    __builtin_amdgcn_global_load_lds((const __attribute__((address_space(1))) u32*)(ag + kt * 32),
        (__attribute__((address_space(3))) u32*)(As + tid * 8), 16, 0, 0);
    __builtin_amdgcn_global_load_lds((const __attribute__((address_space(1))) u32*)(ag + (size_t)64 * K + kt * 32),
        (__attribute__((address_space(3))) u32*)(As + 2048 + tid * 8), 16, 0, 0);
    __builtin_amdgcn_global_load_lds((const __attribute__((address_space(1))) u32*)(bg + kt * 32),
        (__attribute__((address_space(3))) u32*)(Bs + tid * 8), 16, 0, 0);
    __builtin_amdgcn_global_load_lds((const __attribute__((address_space(1))) u32*)(bg + (size_t)64 * K + kt * 32),
        (__attribute__((address_space(3))) u32*)(Bs + 2048 + tid * 8), 16, 0, 0);
    __syncthreads();
    bf16x8 af[4], bf[4];
    #pragma unroll
    for (int f = 0; f < 4; ++f){
      af[f] = *(const bf16x8*)(As + (wm * 64 + f * 16 + l15) * 32 + lq * 8);
      bf[f] = *(const bf16x8*)(Bs + (wn * 64 + f * 16 + l15) * 32 + lq * 8);
    }
    #pragma unroll
    for (int fm = 0; fm < 4; ++fm)
      #pragma unroll
      for (int fn = 0; fn < 4; ++fn)
        acc[fm][fn] = __builtin_amdgcn_mfma_f32_16x16x32_bf16(af[fm], bf[fn], acc[fm][fn], 0, 0, 0);
    __syncthreads();
  }

  float sb[4][4];
  #pragma unroll
  for (int fm = 0; fm < 4; ++fm)
    #pragma unroll
    for (int i = 0; i < 4; ++i)
      sb[fm][i] = sbeta[m0 + wm * 64 + fm * 16 + lq * 4 + i];
  #pragma unroll
  for (int fm = 0; fm < 4; ++fm)
    #pragma unroll
    for (int fn = 0; fn < 4; ++fn)
      #pragma unroll
      for (int i = 0; i < 4; ++i){
        size_t row = (size_t)(m0 + wm * 64 + fm * 16 + lq * 4 + i);
        int col = n0 + wn * 64 + fn * 16 + l15;
        C[row * 4096 + col] = f2b(acc[fm][fn][i] * sb[fm][i]);
      }
}

// ---------------- sparse-flip recurrent update ----------------
__device__ __forceinline__ void do_update(int tid, const u64* __restrict__ khT,
    const u64* fpos, const u64* fneg, u64 flo, u64 fhi, int* acc, float* racc){
  int d0 = 0, d1 = 0, d2 = 0, d3 = 0;
  #pragma unroll
  for (int w2 = 0; w2 < 64; ++w2){
    const u64 fsel = (w2 & 8) ? fhi : flo;
    if (((fsel >> ((w2 & 7) * 8)) & 0xFFull) != 0ull){
      const u64 fp = fpos[w2], fn = fneg[w2];
      const u64* kp = khT + ((size_t)w2 << 12) + tid;
      u64 k0 = kp[0], k1 = kp[1024], k2 = kp[2048], k3 = kp[3072];
      int t0 = __popcll(fp & k0) - __popcll(fn & k0);
      int t1 = __popcll(fp & k1) - __popcll(fn & k1);
      int t2 = __popcll(fp & k2) - __popcll(fn & k2);
      int t3 = __popcll(fp & k3) - __popcll(fn & k3);
      if (w2 < 32){ d0 += t0; d1 += t1; d2 += t2; d3 += t3; }   // excitatory presyn
      else        { d0 -= t0; d1 -= t1; d2 -= t2; d3 -= t3; }   // inhibitory presyn
    }
  }
  acc[0] += d0; acc[1] += d1; acc[2] += d2; acc[3] += d3;
  racc[0] = R_H * (float)acc[0]; racc[1] = R_H * (float)acc[1];
  racc[2] = R_H * (float)acc[2]; racc[3] = R_H * (float)acc[3];
}

// ---------------- the scan: one block per batch, 4 neurons/thread ----------------
__global__ __launch_bounds__(1024) void snn_scan(
    const u16* __restrict__ iin, const u64* __restrict__ khT,
    const float* __restrict__ v0, const float* __restrict__ is0,
    const float* __restrict__ r0, const int* __restrict__ s0,
    float* __restrict__ dout, float* __restrict__ rmean){
  const int b = blockIdx.x, tid = threadIdx.x;
  const int lane = tid & 63, w = tid >> 6;
  __shared__ u64 fpos[64], fneg[64];
  __shared__ u32 wflag[4];

  float v[4], isy[4], rate[4], rsum[4], racc[4];
  int acc[4]; bool prev[4];
  const size_t base = (size_t)b * 4096 + tid;
  const unsigned char* s0b = (const unsigned char*)s0;   // spike0 is all-zero; byte-safe under either layout
  #pragma unroll
  for (int j = 0; j < 4; ++j){
    v[j]    = v0 [base + j * 1024];
    isy[j]  = is0[base + j * 1024];
    rate[j] = r0 [base + j * 1024];
    rsum[j] = 0.f;
    prev[j] = s0b[base + j * 1024] != 0;
    acc[j] = 0; racc[j] = 0.f;
  }
  { // init event: acc = signed_spike0 @ kh
    bool anyp = prev[0] | prev[1] | prev[2] | prev[3];
    bool wany = __any(anyp);
    if (wany){
      #pragma unroll
      for (int j = 0; j < 4; ++j){
        u64 bs = __ballot(prev[j]);
        if (lane == 0){ fpos[j * 16 + w] = bs; fneg[j * 16 + w] = 0ull; }
      }
    }
    if (lane == 0) ((unsigned char*)wflag)[w] = wany ? 1 : 0;
    __syncthreads();
    u32 fa = wflag[0], fb = wflag[1], fc = wflag[2], fd = wflag[3];
    if (fa | fb | fc | fd){
      u64 flo = ((u64)fb << 32) | fa, fhi = ((u64)fd << 32) | fc;
      do_update(tid, khT, fpos, fneg, flo, fhi, acc, racc);
    }
    __syncthreads();
  }

  const u16* ip = iin + (size_t)b * 256 * 4096 + tid;
  u16 curu[4], nxtu[4];
  #pragma unroll
  for (int j = 0; j < 4; ++j) curu[j] = ip[j * 1024];

  for (int t = 0; t < 256; ++t){
    if (t < 255){
      const u16* q = ip + (size_t)(t + 1) * 4096;
      #pragma unroll
      for (int j = 0; j < 4; ++j) nxtu[j] = q[j * 1024];
    }
    bool sn[4];
    #pragma unroll
    for (int j = 0; j < 4; ++j){
      isy[j] = fmaf(isy[j], A_SYN, racc[j]);
      float tv = fmaf(isy[j], BETA, b2f(curu[j]));   // beta*i_syn + beta*R_in*scale*(x@Kin)
      float vv = fmaf(v[j], A_VM, tv);
      sn[j] = vv > 1.0f;
      v[j] = sn[j] ? 0.0f : vv;
      rate[j] = fmaf(rate[j], A_VM, sn[j] ? C_RATE : 0.0f);  // alpha_out == alpha_vm
      rsum[j] += rate[j];
    }
    bool fl0 = sn[0] != prev[0], fl1 = sn[1] != prev[1];
    bool fl2 = sn[2] != prev[2], fl3 = sn[3] != prev[3];
    prev[0] = sn[0]; prev[1] = sn[1]; prev[2] = sn[2]; prev[3] = sn[3];
    bool wany = __any(fl0 | fl1 | fl2 | fl3);
    if (wany){
      #pragma unroll
      for (int j = 0; j < 4; ++j){
        u64 bs = __ballot(sn[j]);
        u64 bfl; { bool f = (j==0)?fl0:(j==1)?fl1:(j==2)?fl2:fl3; bfl = __ballot(f); }
        if (lane == 0){ fpos[j * 16 + w] = bfl & bs; fneg[j * 16 + w] = bfl & ~bs; }
      }
    }
    if (lane == 0) ((unsigned char*)wflag)[w] = wany ? 1 : 0;
    __syncthreads();
    u32 fa = wflag[0], fb = wflag[1], fc = wflag[2], fd = wflag[3];
    if (fa | fb | fc | fd){
      u64 flo = ((u64)fb << 32) | fa, fhi = ((u64)fd << 32) | fc;
      do_update(tid, khT, fpos, fneg, flo, fhi, acc, racc);
    }
    __syncthreads();
    #pragma unroll
    for (int j = 0; j < 4; ++j) curu[j] = nxtu[j];
  }

  #pragma unroll
  for (int j = 0; j < 4; ++j){
    size_t o = base + (size_t)j * 1024;
    dout[o]           = v[j];
    dout[262144 + o]  = isy[j];
    dout[524288 + o]  = rate[j];
    dout[786432 + o]  = prev[j] ? 1.0f : 0.0f;
    rmean[o] = rsum[j] * 0.00390625f;
  }
}

// ---------------- output head: R_out * rate_mean @ (kernel_out & exc_mask) ----------------
__global__ __launch_bounds__(256) void out_gemm(const float* __restrict__ rmean,
                                                const int* __restrict__ ko,
                                                const u32* __restrict__ flag,
                                                float* __restrict__ dout){
  const int b = blockIdx.x;
  const int o = blockIdx.y * 256 + threadIdx.x;
  const bool bm = (*flag) != 0;
  const unsigned char* kob = (const unsigned char*)ko;
  const float* rm = rmean + (size_t)b * 4096;
  float s = 0.f;
  #pragma unroll 8
  for (int n = 0; n < 2048; ++n){
    size_t idx = (size_t)n * 512 + o;
    int kv = bm ? (int)kob[idx] : ko[idx];
    s += rm[n] * (float)kv;
  }
  dout[1048576 + (size_t)b * 512 + o] = R_OUT * s;
}

extern "C" void kernel_launch(void* const* d_in, const int* in_sizes, int n_in,
                              void* d_out, int out_size, void* d_ws, size_t ws_size,
                              hipStream_t stream){
  (void)in_sizes; (void)n_in; (void)out_size; (void)ws_size;
  const float* x   = (const float*)d_in[0];
  const float* v0  = (const float*)d_in[1];
  const float* is0 = (const float*)d_in[2];
  const float* r0  = (const float*)d_in[3];
  const int*   s0  = (const int*)d_in[4];
  const int*   kin = (const int*)d_in[5];
  const int*   kh  = (const int*)d_in[6];
  const int*   ko  = (const int*)d_in[7];
  float* out = (float*)d_out;
  char* ws = (char*)d_ws;

  u16*  xb    = (u16*)(ws);                       // 33,554,432 B
  float* sbeta= (float*)(ws + 33554432);          // 65,536 B
  u16*  iin   = (u16*)(ws + 33619968);            // 134,217,728 B
  u16*  Bt    = (u16*)(ws + 167837696);           // 8,388,608 B
  u64*  khT   = (u64*)(ws + 176226304);           // 2,097,152 B
  float* rmean= (float*)(ws + 178323456);         // 1,048,576 B
  u32*  flag  = (u32*)(ws + 179372032);           // 4 B

  hipMemsetAsync(flag, 0, 4, stream);
  detect_layout<<<dim3(1), dim3(256), 0, stream>>>((const u32*)kh, flag);
  prep_x<<<dim3(16384), dim3(256), 0, stream>>>(x, xb, sbeta);
  prep_bt<<<dim3(16, 64), dim3(256), 0, stream>>>(kin, flag, Bt);
  prep_kh<<<dim3(16, 64), dim3(256), 0, stream>>>(kh, flag, khT);
  gemm_iin<<<dim3(128, 32), dim3(256), 0, stream>>>(xb, Bt, sbeta, iin);
  snn_scan<<<dim3(64), dim3(1024), 0, stream>>>(iin, khT, v0, is0, r0, s0, out, rmean);
  out_gemm<<<dim3(64, 2), dim3(256), 0, stream>>>(rmean, ko, flag, out);
}

// Round 2
// 1870.054 us; speedup vs baseline: 5.5389x; 5.5389x over previous
//
#include <hip/hip_runtime.h>

typedef unsigned short u16;
typedef unsigned int   u32;
typedef unsigned long long u64;

typedef short bf16x8 __attribute__((ext_vector_type(8)));
typedef float f32x4  __attribute__((ext_vector_type(4)));

#define A_SYN  0.90483741803595957f   // exp(-0.5/5)
#define A_VM   0.95122942450071400f   // exp(-0.5/10)
#define BETA   0.04877057549928600f   // 1 - A_VM
#define C_RATE 0.09754115099857200f   // (1/DT)*(1-alpha_out) = 2*BETA
#define R_H    0.04419417382415922f   // 1*1*10/5 * sqrt(1/2048)
#define R_IN   4.41941738241592200f   // 10*1*10 * sqrt(1/512)
#define R_OUT  2.20970869120796080f   // 100 * sqrt(1/2048)

__device__ __forceinline__ u16 f2b(float f){
  u32 x = __float_as_uint(f);
  return (u16)((x + 0x7FFFu + ((x >> 16) & 1u)) >> 16);   // RNE f32->bf16
}
__device__ __forceinline__ float b2f(u16 u){ return __uint_as_float(((u32)u) << 16); }

// ---------------- prep: row sums of x -> sbeta[m]; convert x to bf16 ----------------
__global__ __launch_bounds__(256) void prep_x(const float* __restrict__ x,
                                              u16* __restrict__ xb,
                                              float* __restrict__ sbeta){
  const int m = blockIdx.x;          // 16384 rows
  const int tid = threadIdx.x;       // 256 threads, 4 floats each
  const float4 xv = ((const float4*)(x + (size_t)m * 1024))[tid];
  float s = xv.x + xv.y + xv.z + xv.w;
  #pragma unroll
  for (int off = 32; off > 0; off >>= 1) s += __shfl_down(s, off, 64);
  __shared__ float ps[4];
  if ((tid & 63) == 0) ps[tid >> 6] = s;
  __syncthreads();
  float tot = ps[0] + ps[1] + ps[2] + ps[3];
  float sc = fminf(30.0f / (tot + 1.0f), 10.0f) * (R_IN * BETA);
  if (tid == 0) sbeta[m] = sc;
  ushort4 o; o.x = f2b(xv.x); o.y = f2b(xv.y); o.z = f2b(xv.z); o.w = f2b(xv.w);
  ((ushort4*)(xb + (size_t)m * 1024))[tid] = o;
}

// ---------------- detect bool layout: int32 words (0/1) vs packed bytes ----------------
__global__ void detect_layout(const u32* __restrict__ khw, u32* __restrict__ flag){
  u32 bad = 0;
  #pragma unroll
  for (int i = 0; i < 4; ++i){ u32 v = khw[threadIdx.x + i * 256]; bad |= (v > 1u) ? 1u : 0u; }
  if (bad) *flag = 1u;   // idempotent, deterministic
}

// ---------------- prep: kernel_in -> Bt[n][k] bf16 (transposed) ----------------
__global__ __launch_bounds__(256) void prep_bt(const int* __restrict__ ki,
                                               const u32* __restrict__ flag,
                                               u16* __restrict__ Bt){
  __shared__ u16 tile[64][65];
  const int k0 = blockIdx.x * 64, n0 = blockIdx.y * 64;
  const int tr = threadIdx.x >> 6, tc = threadIdx.x & 63;
  const bool bm = (*flag) != 0;
  const unsigned char* kib = (const unsigned char*)ki;
  #pragma unroll 4
  for (int r = 0; r < 16; ++r){
    int row = r * 4 + tr;
    size_t idx = (size_t)(k0 + row) * 4096 + (n0 + tc);
    int v = bm ? (int)kib[idx] : ki[idx];
    tile[row][tc] = v ? (u16)0x3F80 : (u16)0;
  }
  __syncthreads();
  #pragma unroll 4
  for (int r = 0; r < 16; ++r){
    int row = r * 4 + tr;   // n-local
    Bt[(size_t)(n0 + row) * 1024 + (k0 + tc)] = tile[tc][row];
  }
}

// ---------------- prep: kernel_h -> khT bit-packed [w][n], bit j = kh[w*64+j][n] ----------------
__global__ __launch_bounds__(256) void prep_kh(const int* __restrict__ kh,
                                               const u32* __restrict__ flag,
                                               u64* __restrict__ khT){
  const int n = blockIdx.x * 256 + threadIdx.x;
  const int w = blockIdx.y;
  const bool bm = (*flag) != 0;
  const unsigned char* khb = (const unsigned char*)kh;
  u64 bits = 0;
  #pragma unroll 8
  for (int j = 0; j < 64; ++j){
    size_t idx = (size_t)(w * 64 + j) * 4096 + n;
    int v = bm ? (int)khb[idx] : kh[idx];
    bits |= (u64)(v & 1) << j;
  }
  khT[(size_t)w * 4096 + n] = bits;
}

// ---------------- prep: kernel_h -> khR bit-packed rows [p][w], bit l = kh[p][w*64+l] ----------------
__global__ __launch_bounds__(256) void prep_khR(const int* __restrict__ kh,
                                                const u32* __restrict__ flag,
                                                u64* __restrict__ khR){
  const int p = blockIdx.x * 4 + (threadIdx.x >> 6);   // presyn row
  const int e = threadIdx.x & 63;                      // word over postsyn
  const bool bm = (*flag) != 0;
  u64 bits = 0;
  if (bm){
    const unsigned char* src = (const unsigned char*)kh + (size_t)p * 4096 + e * 64;
    #pragma unroll 8
    for (int l = 0; l < 64; ++l) bits |= (u64)(src[l] & 1) << l;
  } else {
    const int* src = kh + (size_t)p * 4096 + e * 64;
    #pragma unroll 8
    for (int l = 0; l < 64; ++l) bits |= (u64)(src[l] & 1) << l;
  }
  khR[(size_t)p * 64 + e] = bits;
}

// ---------------- bf16 GEMM: i_in_beta[m][n] = bf16(sbeta[m] * sum_k xb[m][k]*Bt[n][k]) ----------------
__global__ __launch_bounds__(256) void gemm_iin(const u16* __restrict__ A,
                                                const u16* __restrict__ Bm,
                                                const float* __restrict__ sbeta,
                                                u16* __restrict__ C){
  __shared__ u16 As[128 * 32];
  __shared__ u16 Bs[128 * 32];
  const int tid = threadIdx.x;
  const int lane = tid & 63, w = tid >> 6;
  const int wm = w >> 1, wn = w & 1;
  const int m0 = blockIdx.x * 128, n0 = blockIdx.y * 128;
  const int l15 = lane & 15, lq = lane >> 4;
  const int K = 1024;

  f32x4 acc[4][4];
  #pragma unroll
  for (int i = 0; i < 4; ++i)
    #pragma unroll
    for (int j = 0; j < 4; ++j) acc[i][j] = (f32x4){0.f, 0.f, 0.f, 0.f};

  const u16* ag = A  + (size_t)(m0 + (tid >> 2)) * K + (tid & 3) * 8;
  const u16* bg = Bm + (size_t)(n0 + (tid >> 2)) * K + (tid & 3) * 8;

  for (int kt = 0; kt < 32; ++kt){
    __builtin_amdgcn_global_load_lds((const __attribute__((address_space(1))) u32*)(ag + kt * 32),
        (__attribute__((address_space(3))) u32*)(As + tid * 8), 16, 0, 0);
    __builtin_amdgcn_global_load_lds((const __attribute__((address_space(1))) u32*)(ag + (size_t)64 * K + kt * 32),
        (__attribute__((address_space(3))) u32*)(As + 2048 + tid * 8), 16, 0, 0);
    __builtin_amdgcn_global_load_lds((const __attribute__((address_space(1))) u32*)(bg + kt * 32),
        (__attribute__((address_space(3))) u32*)(Bs + tid * 8), 16, 0, 0);
    __builtin_amdgcn_global_load_lds((const __attribute__((address_space(1))) u32*)(bg + (size_t)64 * K + kt * 32),
        (__attribute__((address_space(3))) u32*)(Bs + 2048 + tid * 8), 16, 0, 0);
    __syncthreads();
    bf16x8 af[4], bf[4];
    #pragma unroll
    for (int f = 0; f < 4; ++f){
      af[f] = *(const bf16x8*)(As + (wm * 64 + f * 16 + l15) * 32 + lq * 8);
      bf[f] = *(const bf16x8*)(Bs + (wn * 64 + f * 16 + l15) * 32 + lq * 8);
    }
    #pragma unroll
    for (int fm = 0; fm < 4; ++fm)
      #pragma unroll
      for (int fn = 0; fn < 4; ++fn)
        acc[fm][fn] = __builtin_amdgcn_mfma_f32_16x16x32_bf16(af[fm], bf[fn], acc[fm][fn], 0, 0, 0);
    __syncthreads();
  }

  float sb[4][4];
  #pragma unroll
  for (int fm = 0; fm < 4; ++fm)
    #pragma unroll
    for (int i = 0; i < 4; ++i)
      sb[fm][i] = sbeta[m0 + wm * 64 + fm * 16 + lq * 4 + i];
  #pragma unroll
  for (int fm = 0; fm < 4; ++fm)
    #pragma unroll
    for (int fn = 0; fn < 4; ++fn)
      #pragma unroll
      for (int i = 0; i < 4; ++i){
        size_t row = (size_t)(m0 + wm * 64 + fm * 16 + lq * 4 + i);
        int col = n0 + wn * 64 + fn * 16 + l15;
        C[row * 4096 + col] = f2b(acc[fm][fn][i] * sb[fm][i]);
      }
}

// ---------------- mixed sparse/dense recurrent update ----------------
// For each active flip word: few flips -> per-neuron row path (512B/flip, wave-uniform
// broadcast loads); many flips -> word path (32KB strided, t=0 dense event).
__device__ __forceinline__ void do_update_mixed(
    int tid, int w, int lane,
    const u64* __restrict__ khT, const u64* __restrict__ khR,
    const u64* fpos, const u64* fneg, u64 flo, u64 fhi,
    int* acc, float* racc)
{
  #pragma unroll 1
  for (int half = 0; half < 2; ++half){
    u64 m = half ? fhi : flo;
    while (m){
      int bb = ((int)__builtin_ctzll(m)) >> 3;     // lowest active byte = wave index (mod 8)
      m &= ~(0xFFull << (bb * 8));
      int wave = half * 8 + bb;
      #pragma unroll 1
      for (int j = 0; j < 4; ++j){
        int w2 = j * 16 + wave;
        u64 fp = fpos[w2], fn = fneg[w2];
        u64 fa = fp | fn;
        if (fa == 0ull) continue;
        int nf = __popcll(fa);
        if (nf <= 6){
          // sparse: per flipped neuron, read its 512B khR row (uniform per wave)
          while (fa){
            int bit = (int)__builtin_ctzll(fa);
            fa &= fa - 1;
            int p = j * 1024 + wave * 64 + bit;
            int dlt = ((fp >> bit) & 1ull) ? 1 : -1;
            int s = (j < 2) ? dlt : -dlt;            // dale sign: exc iff p<2048 iff j<2
            const u64* row = khR + ((size_t)p << 6) + w;
            u64 r0 = row[0], r1 = row[16], r2 = row[32], r3 = row[48];
            acc[0] += s * (int)((r0 >> lane) & 1ull);
            acc[1] += s * (int)((r1 >> lane) & 1ull);
            acc[2] += s * (int)((r2 >> lane) & 1ull);
            acc[3] += s * (int)((r3 >> lane) & 1ull);
          }
        } else {
          // dense: column-packed popcount path
          const u64* kp = khT + ((size_t)w2 << 12) + tid;
          u64 k0 = kp[0], k1 = kp[1024], k2 = kp[2048], k3 = kp[3072];
          int t0 = __popcll(fp & k0) - __popcll(fn & k0);
          int t1 = __popcll(fp & k1) - __popcll(fn & k1);
          int t2 = __popcll(fp & k2) - __popcll(fn & k2);
          int t3 = __popcll(fp & k3) - __popcll(fn & k3);
          if (j < 2){ acc[0] += t0; acc[1] += t1; acc[2] += t2; acc[3] += t3; }
          else      { acc[0] -= t0; acc[1] -= t1; acc[2] -= t2; acc[3] -= t3; }
        }
      }
    }
  }
  racc[0] = R_H * (float)acc[0]; racc[1] = R_H * (float)acc[1];
  racc[2] = R_H * (float)acc[2]; racc[3] = R_H * (float)acc[3];
}

// ---------------- the scan: one block per batch, 4 neurons/thread ----------------
__global__ __launch_bounds__(1024, 4) void snn_scan(
    const u16* __restrict__ iin, const u64* __restrict__ khT,
    const u64* __restrict__ khR,
    const float* __restrict__ v0, const float* __restrict__ is0,
    const float* __restrict__ r0, const int* __restrict__ s0,
    float* __restrict__ dout, float* __restrict__ rmean){
  const int b = blockIdx.x, tid = threadIdx.x;
  const int lane = tid & 63, w = tid >> 6;
  __shared__ u64 fpos[2][64], fneg[2][64];
  __shared__ u32 wflag[2][4];

  float v[4], isy[4], rate[4], rsum[4], racc[4];
  int acc[4]; bool prev[4];
  const size_t base = (size_t)b * 4096 + tid;
  const unsigned char* s0b = (const unsigned char*)s0;   // spike0 all-zero; byte-safe either layout
  #pragma unroll
  for (int j = 0; j < 4; ++j){
    v[j]    = v0 [base + j * 1024];
    isy[j]  = is0[base + j * 1024];
    rate[j] = r0 [base + j * 1024];
    rsum[j] = 0.f;
    prev[j] = s0b[base + j * 1024] != 0;
    acc[j] = 0; racc[j] = 0.f;
  }

  int buf = 0;
  { // init event: acc = signed_spike0 @ kh (flips = spike0, all-positive)
    bool wany = __any(prev[0] | prev[1] | prev[2] | prev[3]);
    if (wany){
      #pragma unroll
      for (int j = 0; j < 4; ++j){
        u64 bs = __ballot(prev[j]);
        if (lane == 0){ fpos[0][j * 16 + w] = bs; fneg[0][j * 16 + w] = 0ull; }
      }
    }
    if (lane == 0) ((unsigned char*)&wflag[0][0])[w] = wany ? 1 : 0;
    __syncthreads();
    u32 a0 = wflag[0][0], a1 = wflag[0][1], a2 = wflag[0][2], a3 = wflag[0][3];
    u64 flo = ((u64)a1 << 32) | a0, fhi = ((u64)a3 << 32) | a2;
    if (flo | fhi)
      do_update_mixed(tid, w, lane, khT, khR, fpos[0], fneg[0], flo, fhi, acc, racc);
    buf = 1;
  }

  const u16* ip = iin + (size_t)b * 256 * 4096 + tid;
  u16 curu[4], nxtu[4];
  #pragma unroll
  for (int j = 0; j < 4; ++j) curu[j] = ip[j * 1024];

  for (int t = 0; t < 256; ++t){
    if (t < 255){
      const u16* q = ip + (size_t)(t + 1) * 4096;
      #pragma unroll
      for (int j = 0; j < 4; ++j) nxtu[j] = q[j * 1024];
    }
    bool sn[4];
    #pragma unroll
    for (int j = 0; j < 4; ++j){
      isy[j] = fmaf(isy[j], A_SYN, racc[j]);
      float tv = fmaf(isy[j], BETA, b2f(curu[j]));   // beta*i_syn + beta*R_in*scale*(x@Kin)
      float vv = fmaf(v[j], A_VM, tv);
      sn[j] = vv > 1.0f;
      v[j] = sn[j] ? 0.0f : vv;
      rate[j] = fmaf(rate[j], A_VM, sn[j] ? C_RATE : 0.0f);  // alpha_out == alpha_vm
      rsum[j] += rate[j];
    }
    bool fl0 = sn[0] != prev[0], fl1 = sn[1] != prev[1];
    bool fl2 = sn[2] != prev[2], fl3 = sn[3] != prev[3];
    prev[0] = sn[0]; prev[1] = sn[1]; prev[2] = sn[2]; prev[3] = sn[3];
    bool wany = __any(fl0 | fl1 | fl2 | fl3);
    if (wany){
      #pragma unroll
      for (int j = 0; j < 4; ++j){
        u64 bs = __ballot(sn[j]);
        u64 bfl; { bool f = (j==0)?fl0:(j==1)?fl1:(j==2)?fl2:fl3; bfl = __ballot(f); }
        if (lane == 0){ fpos[buf][j * 16 + w] = bfl & bs; fneg[buf][j * 16 + w] = bfl & ~bs; }
      }
    }
    if (lane == 0) ((unsigned char*)&wflag[buf][0])[w] = wany ? 1 : 0;
    __syncthreads();   // single barrier: double-buffered flip state
    u32 a0 = wflag[buf][0], a1 = wflag[buf][1], a2 = wflag[buf][2], a3 = wflag[buf][3];
    if (a0 | a1 | a2 | a3){
      u64 flo = ((u64)a1 << 32) | a0, fhi = ((u64)a3 << 32) | a2;
      do_update_mixed(tid, w, lane, khT, khR, fpos[buf], fneg[buf], flo, fhi, acc, racc);
    }
    buf ^= 1;
    #pragma unroll
    for (int j = 0; j < 4; ++j) curu[j] = nxtu[j];
  }

  #pragma unroll
  for (int j = 0; j < 4; ++j){
    size_t o = base + (size_t)j * 1024;
    dout[o]           = v[j];
    dout[262144 + o]  = isy[j];
    dout[524288 + o]  = rate[j];
    dout[786432 + o]  = prev[j] ? 1.0f : 0.0f;
    rmean[o] = rsum[j] * 0.00390625f;
  }
}

// ---------------- output head: R_out * rate_mean @ (kernel_out & exc_mask) ----------------
__global__ __launch_bounds__(256) void out_gemm(const float* __restrict__ rmean,
                                                const int* __restrict__ ko,
                                                const u32* __restrict__ flag,
                                                float* __restrict__ dout){
  const int b = blockIdx.x;
  const int o = blockIdx.y * 256 + threadIdx.x;
  const bool bm = (*flag) != 0;
  const unsigned char* kob = (const unsigned char*)ko;
  const float* rm = rmean + (size_t)b * 4096;
  float s = 0.f;
  #pragma unroll 8
  for (int n = 0; n < 2048; ++n){
    size_t idx = (size_t)n * 512 + o;
    int kv = bm ? (int)kob[idx] : ko[idx];
    s += rm[n] * (float)kv;
  }
  dout[1048576 + (size_t)b * 512 + o] = R_OUT * s;
}

extern "C" void kernel_launch(void* const* d_in, const int* in_sizes, int n_in,
                              void* d_out, int out_size, void* d_ws, size_t ws_size,
                              hipStream_t stream){
  (void)in_sizes; (void)n_in; (void)out_size; (void)ws_size;
  const float* x   = (const float*)d_in[0];
  const float* v0  = (const float*)d_in[1];
  const float* is0 = (const float*)d_in[2];
  const float* r0  = (const float*)d_in[3];
  const int*   s0  = (const int*)d_in[4];
  const int*   kin = (const int*)d_in[5];
  const int*   kh  = (const int*)d_in[6];
  const int*   ko  = (const int*)d_in[7];
  float* out = (float*)d_out;
  char* ws = (char*)d_ws;

  // rmean overlaps xb: xb is dead after gemm_iin, rmean written by snn_scan afterwards.
  u16*  xb    = (u16*)(ws);                       // [0, 33554432)
  float* rmean= (float*)(ws);                     // [0, 1048576)  lifetime-disjoint with xb
  float* sbeta= (float*)(ws + 33554432);          // 65,536 B
  u16*  iin   = (u16*)(ws + 33619968);            // 134,217,728 B
  u16*  Bt    = (u16*)(ws + 167837696);           // 8,388,608 B
  u64*  khT   = (u64*)(ws + 176226304);           // 2,097,152 B
  u64*  khR   = (u64*)(ws + 178323456);           // 2,097,152 B
  u32*  flag  = (u32*)(ws + 180420608);           // 4 B

  hipMemsetAsync(flag, 0, 4, stream);
  detect_layout<<<dim3(1), dim3(256), 0, stream>>>((const u32*)kh, flag);
  prep_x<<<dim3(16384), dim3(256), 0, stream>>>(x, xb, sbeta);
  prep_bt<<<dim3(16, 64), dim3(256), 0, stream>>>(kin, flag, Bt);
  prep_kh<<<dim3(16, 64), dim3(256), 0, stream>>>(kh, flag, khT);
  prep_khR<<<dim3(1024), dim3(256), 0, stream>>>(kh, flag, khR);
  gemm_iin<<<dim3(128, 32), dim3(256), 0, stream>>>(xb, Bt, sbeta, iin);
  snn_scan<<<dim3(64), dim3(1024), 0, stream>>>(iin, khT, khR, v0, is0, r0, s0, out, rmean);
  out_gemm<<<dim3(64, 2), dim3(256), 0, stream>>>(rmean, ko, flag, out);
}

// Round 3
// 1749.102 us; speedup vs baseline: 5.9219x; 1.0692x over previous
//
#include <hip/hip_runtime.h>

typedef unsigned short u16;
typedef unsigned int   u32;
typedef unsigned long long u64;

typedef short bf16x8 __attribute__((ext_vector_type(8)));
typedef float f32x4  __attribute__((ext_vector_type(4)));

#define A_SYN  0.90483741803595957f   // exp(-0.5/5)
#define A_VM   0.95122942450071400f   // exp(-0.5/10)
#define BETA   0.04877057549928600f   // 1 - A_VM
#define C_RATE 0.09754115099857200f   // (1/DT)*(1-alpha_out) = 2*BETA
#define R_H    0.04419417382415922f   // 1*1*10/5 * sqrt(1/2048)
#define R_IN   4.41941738241592200f   // 10*1*10 * sqrt(1/512)
#define R_OUT  2.20970869120796080f   // 100 * sqrt(1/2048)

#define ECAP 64

__device__ __forceinline__ u16 f2b(float f){
  u32 x = __float_as_uint(f);
  return (u16)((x + 0x7FFFu + ((x >> 16) & 1u)) >> 16);   // RNE f32->bf16
}
__device__ __forceinline__ float b2f(u16 u){ return __uint_as_float(((u32)u) << 16); }

// ---------------- prep: row sums of x -> sbeta[m]; convert x to bf16 ----------------
__global__ __launch_bounds__(256) void prep_x(const float* __restrict__ x,
                                              u16* __restrict__ xb,
                                              float* __restrict__ sbeta){
  const int m = blockIdx.x;          // 16384 rows
  const int tid = threadIdx.x;       // 256 threads, 4 floats each
  const float4 xv = ((const float4*)(x + (size_t)m * 1024))[tid];
  float s = xv.x + xv.y + xv.z + xv.w;
  #pragma unroll
  for (int off = 32; off > 0; off >>= 1) s += __shfl_down(s, off, 64);
  __shared__ float ps[4];
  if ((tid & 63) == 0) ps[tid >> 6] = s;
  __syncthreads();
  float tot = ps[0] + ps[1] + ps[2] + ps[3];
  float sc = fminf(30.0f / (tot + 1.0f), 10.0f) * (R_IN * BETA);
  if (tid == 0) sbeta[m] = sc;
  ushort4 o; o.x = f2b(xv.x); o.y = f2b(xv.y); o.z = f2b(xv.z); o.w = f2b(xv.w);
  ((ushort4*)(xb + (size_t)m * 1024))[tid] = o;
}

// ---------------- detect bool layout: int32 words (0/1) vs packed bytes ----------------
__global__ void detect_layout(const u32* __restrict__ khw, u32* __restrict__ flag){
  u32 bad = 0;
  #pragma unroll
  for (int i = 0; i < 4; ++i){ u32 v = khw[threadIdx.x + i * 256]; bad |= (v > 1u) ? 1u : 0u; }
  if (bad) *flag = 1u;   // idempotent, deterministic
}

// ---------------- prep: kernel_in -> Bt[n][k] bf16 (transposed) ----------------
__global__ __launch_bounds__(256) void prep_bt(const int* __restrict__ ki,
                                               const u32* __restrict__ flag,
                                               u16* __restrict__ Bt){
  __shared__ u16 tile[64][65];
  const int k0 = blockIdx.x * 64, n0 = blockIdx.y * 64;
  const int tr = threadIdx.x >> 6, tc = threadIdx.x & 63;
  const bool bm = (*flag) != 0;
  const unsigned char* kib = (const unsigned char*)ki;
  #pragma unroll 4
  for (int r = 0; r < 16; ++r){
    int row = r * 4 + tr;
    size_t idx = (size_t)(k0 + row) * 4096 + (n0 + tc);
    int v = bm ? (int)kib[idx] : ki[idx];
    tile[row][tc] = v ? (u16)0x3F80 : (u16)0;
  }
  __syncthreads();
  #pragma unroll 4
  for (int r = 0; r < 16; ++r){
    int row = r * 4 + tr;   // n-local
    Bt[(size_t)(n0 + row) * 1024 + (k0 + tc)] = tile[tc][row];
  }
}

// ---------------- prep: kernel_h -> khT bit-packed [w][n], bit j = kh[w*64+j][n] ----------------
__global__ __launch_bounds__(256) void prep_kh(const int* __restrict__ kh,
                                               const u32* __restrict__ flag,
                                               u64* __restrict__ khT){
  const int n = blockIdx.x * 256 + threadIdx.x;
  const int w = blockIdx.y;
  const bool bm = (*flag) != 0;
  const unsigned char* khb = (const unsigned char*)kh;
  u64 bits = 0;
  #pragma unroll 8
  for (int j = 0; j < 64; ++j){
    size_t idx = (size_t)(w * 64 + j) * 4096 + n;
    int v = bm ? (int)khb[idx] : kh[idx];
    bits |= (u64)(v & 1) << j;
  }
  khT[(size_t)w * 4096 + n] = bits;
}

// ---------------- prep: kernel_h -> khR bit-packed rows [p][w], bit l = kh[p][w*64+l] ----------------
__global__ __launch_bounds__(256) void prep_khR(const int* __restrict__ kh,
                                                const u32* __restrict__ flag,
                                                u64* __restrict__ khR){
  const int p = blockIdx.x * 4 + (threadIdx.x >> 6);   // presyn row
  const int e = threadIdx.x & 63;                      // word over postsyn
  const bool bm = (*flag) != 0;
  u64 bits = 0;
  if (bm){
    const unsigned char* src = (const unsigned char*)kh + (size_t)p * 4096 + e * 64;
    #pragma unroll 8
    for (int l = 0; l < 64; ++l) bits |= (u64)(src[l] & 1) << l;
  } else {
    const int* src = kh + (size_t)p * 4096 + e * 64;
    #pragma unroll 8
    for (int l = 0; l < 64; ++l) bits |= (u64)(src[l] & 1) << l;
  }
  khR[(size_t)p * 64 + e] = bits;
}

// ---------------- bf16 GEMM: i_in_beta[m][n] = bf16(sbeta[m] * sum_k xb[m][k]*Bt[n][k]) ----------------
__global__ __launch_bounds__(256) void gemm_iin(const u16* __restrict__ A,
                                                const u16* __restrict__ Bm,
                                                const float* __restrict__ sbeta,
                                                u16* __restrict__ C){
  __shared__ u16 As[128 * 32];
  __shared__ u16 Bs[128 * 32];
  const int tid = threadIdx.x;
  const int lane = tid & 63, w = tid >> 6;
  const int wm = w >> 1, wn = w & 1;
  const int m0 = blockIdx.x * 128, n0 = blockIdx.y * 128;
  const int l15 = lane & 15, lq = lane >> 4;
  const int K = 1024;

  f32x4 acc[4][4];
  #pragma unroll
  for (int i = 0; i < 4; ++i)
    #pragma unroll
    for (int j = 0; j < 4; ++j) acc[i][j] = (f32x4){0.f, 0.f, 0.f, 0.f};

  const u16* ag = A  + (size_t)(m0 + (tid >> 2)) * K + (tid & 3) * 8;
  const u16* bg = Bm + (size_t)(n0 + (tid >> 2)) * K + (tid & 3) * 8;

  for (int kt = 0; kt < 32; ++kt){
    __builtin_amdgcn_global_load_lds((const __attribute__((address_space(1))) u32*)(ag + kt * 32),
        (__attribute__((address_space(3))) u32*)(As + tid * 8), 16, 0, 0);
    __builtin_amdgcn_global_load_lds((const __attribute__((address_space(1))) u32*)(ag + (size_t)64 * K + kt * 32),
        (__attribute__((address_space(3))) u32*)(As + 2048 + tid * 8), 16, 0, 0);
    __builtin_amdgcn_global_load_lds((const __attribute__((address_space(1))) u32*)(bg + kt * 32),
        (__attribute__((address_space(3))) u32*)(Bs + tid * 8), 16, 0, 0);
    __builtin_amdgcn_global_load_lds((const __attribute__((address_space(1))) u32*)(bg + (size_t)64 * K + kt * 32),
        (__attribute__((address_space(3))) u32*)(Bs + 2048 + tid * 8), 16, 0, 0);
    __syncthreads();
    bf16x8 af[4], bf[4];
    #pragma unroll
    for (int f = 0; f < 4; ++f){
      af[f] = *(const bf16x8*)(As + (wm * 64 + f * 16 + l15) * 32 + lq * 8);
      bf[f] = *(const bf16x8*)(Bs + (wn * 64 + f * 16 + l15) * 32 + lq * 8);
    }
    #pragma unroll
    for (int fm = 0; fm < 4; ++fm)
      #pragma unroll
      for (int fn = 0; fn < 4; ++fn)
        acc[fm][fn] = __builtin_amdgcn_mfma_f32_16x16x32_bf16(af[fm], bf[fn], acc[fm][fn], 0, 0, 0);
    __syncthreads();
  }

  float sb[4][4];
  #pragma unroll
  for (int fm = 0; fm < 4; ++fm)
    #pragma unroll
    for (int i = 0; i < 4; ++i)
      sb[fm][i] = sbeta[m0 + wm * 64 + fm * 16 + lq * 4 + i];
  #pragma unroll
  for (int fm = 0; fm < 4; ++fm)
    #pragma unroll
    for (int fn = 0; fn < 4; ++fn)
      #pragma unroll
      for (int i = 0; i < 4; ++i){
        size_t row = (size_t)(m0 + wm * 64 + fm * 16 + lq * 4 + i);
        int col = n0 + wn * 64 + fn * 16 + l15;
        C[row * 4096 + col] = f2b(acc[fm][fn][i] * sb[fm][i]);
      }
}

// ---------------- sparse path: batched independent khR loads over the event list ----------------
__device__ __forceinline__ void apply_events(
    int w, int lane, const u64* __restrict__ khR,
    const u32* __restrict__ elist, int cnt, int* acc)
{
  int e = 0;
  while (e < cnt){
    int n = cnt - e; if (n > 8) n = 8;
    u32 ee[8]; u64 r0[8], r1[8], r2[8], r3[8];
    #pragma unroll
    for (int i = 0; i < 8; ++i) if (i < n) ee[i] = elist[e + i];      // LDS broadcast
    #pragma unroll
    for (int i = 0; i < 8; ++i) if (i < n){
      const u64* row = khR + ((size_t)(ee[i] & 4095u) << 6) + w;       // wave-uniform
      r0[i] = row[0]; r1[i] = row[16]; r2[i] = row[32]; r3[i] = row[48];
    }
    #pragma unroll
    for (int i = 0; i < 8; ++i) if (i < n){
      int b0 = (int)((r0[i] >> lane) & 1ull), b1 = (int)((r1[i] >> lane) & 1ull);
      int b2 = (int)((r2[i] >> lane) & 1ull), b3 = (int)((r3[i] >> lane) & 1ull);
      if (ee[i] & 0x1000u){ acc[0] -= b0; acc[1] -= b1; acc[2] -= b2; acc[3] -= b3; }
      else                { acc[0] += b0; acc[1] += b1; acc[2] += b2; acc[3] += b3; }
    }
    e += 8;
  }
}

// ---------------- dense fallback: column-packed popcount over all active words ----------------
__device__ __forceinline__ void do_update_dense(
    int tid, const u64* __restrict__ khT,
    const u64* __restrict__ fpos, const u64* __restrict__ fneg, int* acc)
{
  #pragma unroll 1
  for (int w2 = 0; w2 < 64; ++w2){
    u64 fp = fpos[w2], fn = fneg[w2];
    if ((fp | fn) == 0ull) continue;
    const u64* kp = khT + ((size_t)w2 << 12) + tid;
    u64 k0 = kp[0], k1 = kp[1024], k2 = kp[2048], k3 = kp[3072];
    int t0 = __popcll(fp & k0) - __popcll(fn & k0);
    int t1 = __popcll(fp & k1) - __popcll(fn & k1);
    int t2 = __popcll(fp & k2) - __popcll(fn & k2);
    int t3 = __popcll(fp & k3) - __popcll(fn & k3);
    if (w2 < 32){ acc[0] += t0; acc[1] += t1; acc[2] += t2; acc[3] += t3; }
    else        { acc[0] -= t0; acc[1] -= t1; acc[2] -= t2; acc[3] -= t3; }
  }
}

// ---------------- the scan: one block per batch, 4 neurons/thread, event-list protocol ----------------
__global__ __launch_bounds__(1024, 4) void snn_scan(
    const u16* __restrict__ iin, const u64* __restrict__ khT,
    const u64* __restrict__ khR,
    const float* __restrict__ v0, const float* __restrict__ is0,
    const float* __restrict__ r0, const int* __restrict__ s0,
    float* __restrict__ dout, float* __restrict__ rmean){
  const int b = blockIdx.x, tid = threadIdx.x;
  const int lane = tid & 63, w = tid >> 6;
  __shared__ u64 fpos[2][64], fneg[2][64];
  __shared__ u32 elist[4][ECAP];
  __shared__ int ecnt[4];

  if (tid < 4) ecnt[tid] = 0;

  float v[4], isy[4], rate[4], rsum[4], racc[4];
  int acc[4]; bool prev[4];
  const size_t base = (size_t)b * 4096 + tid;
  const unsigned char* s0b = (const unsigned char*)s0;   // spike0 all-zero; byte-safe either layout
  #pragma unroll
  for (int j = 0; j < 4; ++j){
    v[j]    = v0 [base + j * 1024];
    isy[j]  = is0[base + j * 1024];
    rate[j] = r0 [base + j * 1024];
    rsum[j] = 0.f;
    prev[j] = s0b[base + j * 1024] != 0;
    acc[j] = 0; racc[j] = 0.f;
  }
  __syncthreads();   // ecnt zeroed before any producer

  { // init event (step -1): flips = spike0 rising; mbuf=1, ebuf=3
    u64 bsp[4];
    #pragma unroll
    for (int j = 0; j < 4; ++j) bsp[j] = __ballot(prev[j]);
    if (lane == 0){
      int tot = 0;
      #pragma unroll
      for (int j = 0; j < 4; ++j){
        fpos[1][j * 16 + w] = bsp[j]; fneg[1][j * 16 + w] = 0ull;
        tot += __popcll(bsp[j]);
      }
      if (tot){
        int basev = atomicAdd(&ecnt[3], tot);
        if (basev + tot <= ECAP){
          int idx = basev;
          #pragma unroll
          for (int j = 0; j < 4; ++j){
            u64 m = bsp[j];
            while (m){
              int bit = (int)__builtin_ctzll(m); m &= m - 1;
              u32 p = (u32)(j * 1024 + w * 64 + bit);
              u32 neg = (j < 2) ? 0u : 1u;           // rising only
              elist[3][idx++] = p | (neg << 12);
            }
          }
        }
      }
    }
    __syncthreads();
    int cnt = ecnt[3];
    if (cnt){
      if (cnt <= ECAP) apply_events(w, lane, khR, elist[3], cnt, acc);
      else             do_update_dense(tid, khT, fpos[1], fneg[1], acc);
      racc[0] = R_H * (float)acc[0]; racc[1] = R_H * (float)acc[1];
      racc[2] = R_H * (float)acc[2]; racc[3] = R_H * (float)acc[3];
    }
  }

  const u16* ip = iin + (size_t)b * 256 * 4096 + tid;
  u16 curu[4], nxtu[4], nx2u[4];
  #pragma unroll
  for (int j = 0; j < 4; ++j) curu[j] = ip[j * 1024];
  #pragma unroll
  for (int j = 0; j < 4; ++j) nxtu[j] = ip[4096 + j * 1024];

  for (int t = 0; t < 256; ++t){
    const int mbuf = t & 1, ebuf = t & 3;
    if (t < 254){
      const u16* q = ip + (size_t)(t + 2) * 4096;
      #pragma unroll
      for (int j = 0; j < 4; ++j) nx2u[j] = q[j * 1024];
    }
    bool sn[4];
    #pragma unroll
    for (int j = 0; j < 4; ++j){
      isy[j] = fmaf(isy[j], A_SYN, racc[j]);
      float tv = fmaf(isy[j], BETA, b2f(curu[j]));   // beta*i_syn + beta*R_in*scale*(x@Kin)
      float vv = fmaf(v[j], A_VM, tv);
      sn[j] = vv > 1.0f;
      v[j] = sn[j] ? 0.0f : vv;
      rate[j] = fmaf(rate[j], A_VM, sn[j] ? C_RATE : 0.0f);  // alpha_out == alpha_vm
      rsum[j] += rate[j];
    }
    u64 bsp[4], bfl[4];
    #pragma unroll
    for (int j = 0; j < 4; ++j){
      bsp[j] = __ballot(sn[j]);
      bfl[j] = __ballot(sn[j] != prev[j]);
      prev[j] = sn[j];
    }
    if (lane == 0){
      int tot = 0;
      #pragma unroll
      for (int j = 0; j < 4; ++j){
        fpos[mbuf][j * 16 + w] = bfl[j] & bsp[j];
        fneg[mbuf][j * 16 + w] = bfl[j] & ~bsp[j];
        tot += __popcll(bfl[j]);
      }
      if (tot){
        int basev = atomicAdd(&ecnt[ebuf], tot);
        if (basev + tot <= ECAP){
          int idx = basev;
          #pragma unroll
          for (int j = 0; j < 4; ++j){
            u64 m = bfl[j];
            while (m){
              int bit = (int)__builtin_ctzll(m); m &= m - 1;
              u32 p = (u32)(j * 1024 + w * 64 + bit);
              u32 rising = (u32)((bsp[j] >> bit) & 1ull);
              u32 neg = (j < 2) ? (rising ^ 1u) : rising;   // dale sign
              elist[ebuf][idx++] = p | (neg << 12);
            }
          }
        }
      }
    }
    __syncthreads();   // single barrier per step
    int cnt = ecnt[ebuf];
    if (cnt){
      if (cnt <= ECAP) apply_events(w, lane, khR, elist[ebuf], cnt, acc);
      else             do_update_dense(tid, khT, fpos[mbuf], fneg[mbuf], acc);
      racc[0] = R_H * (float)acc[0]; racc[1] = R_H * (float)acc[1];
      racc[2] = R_H * (float)acc[2]; racc[3] = R_H * (float)acc[3];
    }
    if (tid == 0) ecnt[(t + 2) & 3] = 0;   // safe: producers of this slot are 2 barriers away
    #pragma unroll
    for (int j = 0; j < 4; ++j){ curu[j] = nxtu[j]; nxtu[j] = nx2u[j]; }
  }

  #pragma unroll
  for (int j = 0; j < 4; ++j){
    size_t o = base + (size_t)j * 1024;
    dout[o]           = v[j];
    dout[262144 + o]  = isy[j];
    dout[524288 + o]  = rate[j];
    dout[786432 + o]  = prev[j] ? 1.0f : 0.0f;
    rmean[o] = rsum[j] * 0.00390625f;
  }
}

// ---------------- output head: R_out * rate_mean @ (kernel_out & exc_mask) ----------------
__global__ __launch_bounds__(256) void out_gemm(const float* __restrict__ rmean,
                                                const int* __restrict__ ko,
                                                const u32* __restrict__ flag,
                                                float* __restrict__ dout){
  const int b = blockIdx.x;
  const int o = blockIdx.y * 256 + threadIdx.x;
  const bool bm = (*flag) != 0;
  const unsigned char* kob = (const unsigned char*)ko;
  const float* rm = rmean + (size_t)b * 4096;
  float s = 0.f;
  #pragma unroll 8
  for (int n = 0; n < 2048; ++n){
    size_t idx = (size_t)n * 512 + o;
    int kv = bm ? (int)kob[idx] : ko[idx];
    s += rm[n] * (float)kv;
  }
  dout[1048576 + (size_t)b * 512 + o] = R_OUT * s;
}

extern "C" void kernel_launch(void* const* d_in, const int* in_sizes, int n_in,
                              void* d_out, int out_size, void* d_ws, size_t ws_size,
                              hipStream_t stream){
  (void)in_sizes; (void)n_in; (void)out_size; (void)ws_size;
  const float* x   = (const float*)d_in[0];
  const float* v0  = (const float*)d_in[1];
  const float* is0 = (const float*)d_in[2];
  const float* r0  = (const float*)d_in[3];
  const int*   s0  = (const int*)d_in[4];
  const int*   kin = (const int*)d_in[5];
  const int*   kh  = (const int*)d_in[6];
  const int*   ko  = (const int*)d_in[7];
  float* out = (float*)d_out;
  char* ws = (char*)d_ws;

  // rmean overlaps xb: xb is dead after gemm_iin, rmean written by snn_scan afterwards.
  u16*  xb    = (u16*)(ws);                       // [0, 33554432)
  float* rmean= (float*)(ws);                     // [0, 1048576)  lifetime-disjoint with xb
  float* sbeta= (float*)(ws + 33554432);          // 65,536 B
  u16*  iin   = (u16*)(ws + 33619968);            // 134,217,728 B
  u16*  Bt    = (u16*)(ws + 167837696);           // 8,388,608 B
  u64*  khT   = (u64*)(ws + 176226304);           // 2,097,152 B
  u64*  khR   = (u64*)(ws + 178323456);           // 2,097,152 B
  u32*  flag  = (u32*)(ws + 180420608);           // 4 B

  hipMemsetAsync(flag, 0, 4, stream);
  detect_layout<<<dim3(1), dim3(256), 0, stream>>>((const u32*)kh, flag);
  prep_x<<<dim3(16384), dim3(256), 0, stream>>>(x, xb, sbeta);
  prep_bt<<<dim3(16, 64), dim3(256), 0, stream>>>(kin, flag, Bt);
  prep_kh<<<dim3(16, 64), dim3(256), 0, stream>>>(kh, flag, khT);
  prep_khR<<<dim3(1024), dim3(256), 0, stream>>>(kh, flag, khR);
  gemm_iin<<<dim3(128, 32), dim3(256), 0, stream>>>(xb, Bt, sbeta, iin);
  snn_scan<<<dim3(64), dim3(1024), 0, stream>>>(iin, khT, khR, v0, is0, r0, s0, out, rmean);
  out_gemm<<<dim3(64, 2), dim3(256), 0, stream>>>(rmean, ko, flag, out);
}

// Round 4
// 1585.735 us; speedup vs baseline: 6.5320x; 1.1030x over previous
//
#include <hip/hip_runtime.h>

typedef unsigned short u16;
typedef unsigned int   u32;
typedef unsigned long long u64;

typedef short bf16x8 __attribute__((ext_vector_type(8)));
typedef float f32x4  __attribute__((ext_vector_type(4)));

#define A_SYN  0.90483741803595957f   // exp(-0.5/5)
#define A_VM   0.95122942450071400f   // exp(-0.5/10)
#define BETA   0.04877057549928600f   // 1 - A_VM
#define C_RATE 0.09754115099857200f   // (1/DT)*(1-alpha_out) = 2*BETA
#define R_H    0.04419417382415922f   // 1*1*10/5 * sqrt(1/2048)
#define R_IN   4.41941738241592200f   // 10*1*10 * sqrt(1/512)
#define R_OUT  2.20970869120796080f   // 100 * sqrt(1/2048)

#define ECAP 32

__device__ __forceinline__ u16 f2b(float f){
  u32 x = __float_as_uint(f);
  return (u16)((x + 0x7FFFu + ((x >> 16) & 1u)) >> 16);   // RNE f32->bf16
}
__device__ __forceinline__ float b2f(u16 u){ return __uint_as_float(((u32)u) << 16); }

// ---------------- prep: row sums of x -> sbeta[m]; convert x to bf16 ----------------
__global__ __launch_bounds__(256) void prep_x(const float* __restrict__ x,
                                              u16* __restrict__ xb,
                                              float* __restrict__ sbeta){
  const int m = blockIdx.x;
  const int tid = threadIdx.x;
  const float4 xv = ((const float4*)(x + (size_t)m * 1024))[tid];
  float s = xv.x + xv.y + xv.z + xv.w;
  #pragma unroll
  for (int off = 32; off > 0; off >>= 1) s += __shfl_down(s, off, 64);
  __shared__ float ps[4];
  if ((tid & 63) == 0) ps[tid >> 6] = s;
  __syncthreads();
  float tot = ps[0] + ps[1] + ps[2] + ps[3];
  float sc = fminf(30.0f / (tot + 1.0f), 10.0f) * (R_IN * BETA);
  if (tid == 0) sbeta[m] = sc;
  ushort4 o; o.x = f2b(xv.x); o.y = f2b(xv.y); o.z = f2b(xv.z); o.w = f2b(xv.w);
  ((ushort4*)(xb + (size_t)m * 1024))[tid] = o;
}

// ---------------- detect bool layout: int32 words (0/1) vs packed bytes ----------------
__global__ void detect_layout(const u32* __restrict__ khw, u32* __restrict__ flag){
  u32 bad = 0;
  #pragma unroll
  for (int i = 0; i < 4; ++i){ u32 v = khw[threadIdx.x + i * 256]; bad |= (v > 1u) ? 1u : 0u; }
  if (bad) *flag = 1u;
}

// ---------------- prep: kernel_in -> Bt[n][k] bf16 (transposed) ----------------
__global__ __launch_bounds__(256) void prep_bt(const int* __restrict__ ki,
                                               const u32* __restrict__ flag,
                                               u16* __restrict__ Bt){
  __shared__ u16 tile[64][65];
  const int k0 = blockIdx.x * 64, n0 = blockIdx.y * 64;
  const int tr = threadIdx.x >> 6, tc = threadIdx.x & 63;
  const bool bm = (*flag) != 0;
  const unsigned char* kib = (const unsigned char*)ki;
  #pragma unroll 4
  for (int r = 0; r < 16; ++r){
    int row = r * 4 + tr;
    size_t idx = (size_t)(k0 + row) * 4096 + (n0 + tc);
    int v = bm ? (int)kib[idx] : ki[idx];
    tile[row][tc] = v ? (u16)0x3F80 : (u16)0;
  }
  __syncthreads();
  #pragma unroll 4
  for (int r = 0; r < 16; ++r){
    int row = r * 4 + tr;
    Bt[(size_t)(n0 + row) * 1024 + (k0 + tc)] = tile[tc][row];
  }
}

// ---------------- prep: kernel_h -> khT bit-packed [w][n], bit j = kh[w*64+j][n] ----------------
__global__ __launch_bounds__(256) void prep_kh(const int* __restrict__ kh,
                                               const u32* __restrict__ flag,
                                               u64* __restrict__ khT){
  const int n = blockIdx.x * 256 + threadIdx.x;
  const int w = blockIdx.y;
  const bool bm = (*flag) != 0;
  const unsigned char* khb = (const unsigned char*)kh;
  u64 bits = 0;
  #pragma unroll 8
  for (int j = 0; j < 64; ++j){
    size_t idx = (size_t)(w * 64 + j) * 4096 + n;
    int v = bm ? (int)khb[idx] : kh[idx];
    bits |= (u64)(v & 1) << j;
  }
  khT[(size_t)w * 4096 + n] = bits;
}

// ---------------- prep: kernel_h -> khR bit-packed rows [p][w], bit l = kh[p][w*64+l] ----------------
__global__ __launch_bounds__(256) void prep_khR(const int* __restrict__ kh,
                                                const u32* __restrict__ flag,
                                                u64* __restrict__ khR){
  const int p = blockIdx.x * 4 + (threadIdx.x >> 6);
  const int e = threadIdx.x & 63;
  const bool bm = (*flag) != 0;
  u64 bits = 0;
  if (bm){
    const unsigned char* src = (const unsigned char*)kh + (size_t)p * 4096 + e * 64;
    #pragma unroll 8
    for (int l = 0; l < 64; ++l) bits |= (u64)(src[l] & 1) << l;
  } else {
    const int* src = kh + (size_t)p * 4096 + e * 64;
    #pragma unroll 8
    for (int l = 0; l < 64; ++l) bits |= (u64)(src[l] & 1) << l;
  }
  khR[(size_t)p * 64 + e] = bits;
}

// ---------------- bf16 GEMM: i_in_beta[m][n] = bf16(sbeta[m] * sum_k xb[m][k]*Bt[n][k]) ----------------
__global__ __launch_bounds__(256) void gemm_iin(const u16* __restrict__ A,
                                                const u16* __restrict__ Bm,
                                                const float* __restrict__ sbeta,
                                                u16* __restrict__ C){
  __shared__ u16 As[128 * 32];
  __shared__ u16 Bs[128 * 32];
  const int tid = threadIdx.x;
  const int lane = tid & 63, w = tid >> 6;
  const int wm = w >> 1, wn = w & 1;
  const int m0 = blockIdx.x * 128, n0 = blockIdx.y * 128;
  const int l15 = lane & 15, lq = lane >> 4;
  const int K = 1024;

  f32x4 acc[4][4];
  #pragma unroll
  for (int i = 0; i < 4; ++i)
    #pragma unroll
    for (int j = 0; j < 4; ++j) acc[i][j] = (f32x4){0.f, 0.f, 0.f, 0.f};

  const u16* ag = A  + (size_t)(m0 + (tid >> 2)) * K + (tid & 3) * 8;
  const u16* bg = Bm + (size_t)(n0 + (tid >> 2)) * K + (tid & 3) * 8;

  for (int kt = 0; kt < 32; ++kt){
    __builtin_amdgcn_global_load_lds((const __attribute__((address_space(1))) u32*)(ag + kt * 32),
        (__attribute__((address_space(3))) u32*)(As + tid * 8), 16, 0, 0);
    __builtin_amdgcn_global_load_lds((const __attribute__((address_space(1))) u32*)(ag + (size_t)64 * K + kt * 32),
        (__attribute__((address_space(3))) u32*)(As + 2048 + tid * 8), 16, 0, 0);
    __builtin_amdgcn_global_load_lds((const __attribute__((address_space(1))) u32*)(bg + kt * 32),
        (__attribute__((address_space(3))) u32*)(Bs + tid * 8), 16, 0, 0);
    __builtin_amdgcn_global_load_lds((const __attribute__((address_space(1))) u32*)(bg + (size_t)64 * K + kt * 32),
        (__attribute__((address_space(3))) u32*)(Bs + 2048 + tid * 8), 16, 0, 0);
    __syncthreads();
    bf16x8 af[4], bf[4];
    #pragma unroll
    for (int f = 0; f < 4; ++f){
      af[f] = *(const bf16x8*)(As + (wm * 64 + f * 16 + l15) * 32 + lq * 8);
      bf[f] = *(const bf16x8*)(Bs + (wn * 64 + f * 16 + l15) * 32 + lq * 8);
    }
    #pragma unroll
    for (int fm = 0; fm < 4; ++fm)
      #pragma unroll
      for (int fn = 0; fn < 4; ++fn)
        acc[fm][fn] = __builtin_amdgcn_mfma_f32_16x16x32_bf16(af[fm], bf[fn], acc[fm][fn], 0, 0, 0);
    __syncthreads();
  }

  float sb[4][4];
  #pragma unroll
  for (int fm = 0; fm < 4; ++fm)
    #pragma unroll
    for (int i = 0; i < 4; ++i)
      sb[fm][i] = sbeta[m0 + wm * 64 + fm * 16 + lq * 4 + i];
  #pragma unroll
  for (int fm = 0; fm < 4; ++fm)
    #pragma unroll
    for (int fn = 0; fn < 4; ++fn)
      #pragma unroll
      for (int i = 0; i < 4; ++i){
        size_t row = (size_t)(m0 + wm * 64 + fm * 16 + lq * 4 + i);
        int col = n0 + wn * 64 + fn * 16 + l15;
        C[row * 4096 + col] = f2b(acc[fm][fn][i] * sb[fm][i]);
      }
}

// ================= SNN scan: 512 threads, 8 neurons/thread (n = tid + 512j) =================

// producer: lane0 of each wave publishes flip masks + events
__device__ __forceinline__ void produce(
    int lane, int w, int mbuf, int ebuf,
    const u64 (&bsp)[8], const u64 (&bfl)[8], bool wany,
    u64 (*fpos)[64], u64 (*fneg)[64], u64* mvalid,
    u32 (*elist)[ECAP], int* ecnt)
{
  if (lane == 0){
    ((unsigned char*)&mvalid[mbuf])[w] = wany ? 1 : 0;
    if (wany){
      int tot = 0;
      #pragma unroll
      for (int j = 0; j < 8; ++j){
        fpos[mbuf][w + 8 * j] = bfl[j] & bsp[j];
        fneg[mbuf][w + 8 * j] = bfl[j] & ~bsp[j];
        tot += __popcll(bfl[j]);
      }
      int basei = atomicAdd(&ecnt[ebuf], tot);
      if (basei + tot <= ECAP){
        int idx = basei;
        #pragma unroll 1
        for (int j = 0; j < 8; ++j){
          u64 m = bfl[j];
          while (m){
            int bit = (int)__builtin_ctzll(m); m &= m - 1;
            u32 p = (u32)(j * 512 + w * 64 + bit);
            u32 rising = (u32)((bsp[j] >> bit) & 1ull);
            u32 neg = (j < 4) ? (rising ^ 1u) : rising;   // exc iff j<4 (p<2048)
            elist[ebuf][idx++] = p | (neg << 12);
          }
        }
      }
    }
  }
}

// consumer: apply events via hot-row register cache (miss -> fill from khR); dense via khT
__device__ __forceinline__ void consume(
    int tid, int lane, int w, int mbuf, int ebuf,
    const u64* __restrict__ khT, const u64* __restrict__ khR,
    u64 (*fpos)[64], u64 (*fneg)[64], const u64* mvalid,
    u32 (*elist)[ECAP], int* ecnt, u32* tag,
    int (&acc)[8], float (&racc)[8], u64 (&hotbits)[8])
{
  int cnt = ecnt[ebuf];
  if (cnt == 0) return;
  if (cnt <= ECAP){
    u64 dirty = 0ull;
    #pragma unroll
    for (int c = 0; c < 8; ++c){
      if (c * 4 < cnt){
        uint4 q = ((const uint4*)&elist[ebuf][0])[c];
        u32 evs[4] = {q.x, q.y, q.z, q.w};
        #pragma unroll
        for (int i = 0; i < 4; ++i){
          if (c * 4 + i < cnt){
            u32 ev = evs[i];
            u32 p = ev & 4095u, neg = (ev >> 12) & 1u;
            u32 s = (p ^ (p >> 6)) & 63u;
            u32 tg = tag[s];
            int sg = neg ? -1 : 1;
            bool hit = (tg == p) && !((dirty >> s) & 1ull);
            if (hit){
              #pragma unroll
              for (int j = 0; j < 8; ++j)
                acc[j] += sg * (int)((hotbits[j] >> s) & 1ull);
            } else {
              const u64* rp = khR + ((size_t)p << 6) + w;
              u64 sm = 1ull << s;
              #pragma unroll
              for (int j = 0; j < 8; ++j){
                u64 r = rp[8 * j];                       // wave-uniform word
                u64 bit = (r >> lane) & 1ull;
                acc[j] += sg * (int)bit;
                hotbits[j] = (hotbits[j] & ~sm) | (bit << s);
              }
              if (tid == 0) tag[s] = p;                  // visible next step
              dirty |= sm;
            }
          }
        }
      }
    }
  } else {
    u64 mv = mvalid[mbuf];
    #pragma unroll 1
    for (int w2 = 0; w2 < 64; ++w2){
      if (((mv >> ((w2 & 7) * 8)) & 0xFFull) == 0ull) continue;
      u64 fp = fpos[mbuf][w2], fn = fneg[mbuf][w2];
      if ((fp | fn) == 0ull) continue;
      const u64* kp = khT + ((size_t)w2 << 12) + tid;
      #pragma unroll
      for (int j = 0; j < 8; ++j){
        u64 k = kp[512 * j];
        int tt = __popcll(fp & k) - __popcll(fn & k);
        acc[j] += (w2 < 32) ? tt : -tt;
      }
    }
  }
  #pragma unroll
  for (int j = 0; j < 8; ++j) racc[j] = R_H * (float)acc[j];
}

// one timestep (cur = this step's iin values; refills cur for step t+2 after use)
__device__ __forceinline__ void snn_step(
    int t, int tid, int lane, int w, const u16* __restrict__ ip,
    const u64* __restrict__ khT, const u64* __restrict__ khR,
    u16 (&cur)[8],
    float (&v)[8], float (&isy)[8], float (&rate)[8], float (&rsum)[8],
    float (&racc)[8], int (&acc)[8], bool (&prev)[8], u64 (&hotbits)[8],
    u64 (*fpos)[64], u64 (*fneg)[64], u64* mvalid,
    u32 (*elist)[ECAP], int* ecnt, u32* tag)
{
  const int mbuf = t & 1, ebuf = t & 3;
  bool sn[8];
  #pragma unroll
  for (int j = 0; j < 8; ++j){
    isy[j] = fmaf(isy[j], A_SYN, racc[j]);
    float tv = fmaf(isy[j], BETA, b2f(cur[j]));   // beta*i_syn + beta*R_in*scale*(x@Kin)
    float vv = fmaf(v[j], A_VM, tv);
    sn[j] = vv > 1.0f;
    v[j] = sn[j] ? 0.0f : vv;
    rate[j] = fmaf(rate[j], A_VM, sn[j] ? C_RATE : 0.0f);  // alpha_out == alpha_vm
    rsum[j] += rate[j];
  }
  // refill cur for t+2 (consumed 2 steps later; no register rotation)
  if (t + 2 < 256){
    const u16* q = ip + (size_t)(t + 2) * 4096;
    #pragma unroll
    for (int j = 0; j < 8; ++j) cur[j] = q[j * 512];
  }
  u64 bsp[8], bfl[8]; bool anyf = false;
  #pragma unroll
  for (int j = 0; j < 8; ++j){
    bsp[j] = __ballot(sn[j]);
    bfl[j] = __ballot(sn[j] != prev[j]);
    anyf |= (sn[j] != prev[j]);
    prev[j] = sn[j];
  }
  bool wany = __any(anyf);
  produce(lane, w, mbuf, ebuf, bsp, bfl, wany, fpos, fneg, mvalid, elist, ecnt);
  __syncthreads();   // single barrier per step (all other LDS slots are rotation-disjoint)
  consume(tid, lane, w, mbuf, ebuf, khT, khR, fpos, fneg, mvalid, elist, ecnt, tag,
          acc, racc, hotbits);
  if (tid == 0) ecnt[(t + 2) & 3] = 0;   // producers of this slot are a barrier away
}

__global__ __launch_bounds__(512, 2) void snn_scan(
    const u16* __restrict__ iin, const u64* __restrict__ khT,
    const u64* __restrict__ khR,
    const float* __restrict__ v0, const float* __restrict__ is0,
    const float* __restrict__ r0, const int* __restrict__ s0,
    float* __restrict__ dout, float* __restrict__ rmean)
{
  const int b = blockIdx.x, tid = threadIdx.x;
  const int lane = tid & 63, w = tid >> 6;     // 8 waves
  __shared__ __align__(16) u32 elist[4][ECAP];
  __shared__ u64 fpos[2][64], fneg[2][64];
  __shared__ u32 tag[64];
  __shared__ u64 mvalid[2];
  __shared__ int ecnt[4];

  if (tid < 4) ecnt[tid] = 0;
  if (tid < 64) tag[tid] = 0xFFFFFFFFu;

  float v[8], isy[8], rate[8], rsum[8], racc[8];
  int acc[8]; bool prev[8]; u64 hotbits[8];
  const size_t base = (size_t)b * 4096 + tid;
  const unsigned char* s0b = (const unsigned char*)s0;   // spike0 all-zero; byte-safe either layout
  #pragma unroll
  for (int j = 0; j < 8; ++j){
    v[j]    = v0 [base + j * 512];
    isy[j]  = is0[base + j * 512];
    rate[j] = r0 [base + j * 512];
    rsum[j] = 0.f;
    prev[j] = s0b[base + j * 512] != 0;
    acc[j] = 0; racc[j] = 0.f; hotbits[j] = 0ull;
  }
  __syncthreads();   // ecnt/tag initialized

  { // init event: acc = signed_spike0 @ kh (rising flips only); mbuf=1, ebuf=3
    u64 bsp[8], bfl[8]; bool anyf = false;
    #pragma unroll
    for (int j = 0; j < 8; ++j){ bsp[j] = __ballot(prev[j]); bfl[j] = bsp[j]; anyf |= prev[j]; }
    bool wany = __any(anyf);
    produce(lane, w, 1, 3, bsp, bfl, wany, fpos, fneg, mvalid, elist, ecnt);
    __syncthreads();
    consume(tid, lane, w, 1, 3, khT, khR, fpos, fneg, mvalid, elist, ecnt, tag,
            acc, racc, hotbits);
    // ecnt[3] is re-zeroed at logical step 1 ((1+3)&3); slots 0..2 still zero
  }

  const u16* ip = iin + (size_t)b * 256 * 4096 + tid;
  u16 bufA[8], bufB[8];
  #pragma unroll
  for (int j = 0; j < 8; ++j) bufA[j] = ip[j * 512];
  #pragma unroll
  for (int j = 0; j < 8; ++j) bufB[j] = ip[4096 + j * 512];

  for (int t = 0; t < 256; t += 2){
    snn_step(t,     tid, lane, w, ip, khT, khR, bufA,
             v, isy, rate, rsum, racc, acc, prev, hotbits,
             fpos, fneg, mvalid, elist, ecnt, tag);
    snn_step(t + 1, tid, lane, w, ip, khT, khR, bufB,
             v, isy, rate, rsum, racc, acc, prev, hotbits,
             fpos, fneg, mvalid, elist, ecnt, tag);
  }

  #pragma unroll
  for (int j = 0; j < 8; ++j){
    size_t o = base + (size_t)j * 512;
    dout[o]           = v[j];
    dout[262144 + o]  = isy[j];
    dout[524288 + o]  = rate[j];
    dout[786432 + o]  = prev[j] ? 1.0f : 0.0f;
    rmean[o] = rsum[j] * 0.00390625f;
  }
}

// ---------------- output head: R_out * rate_mean @ (kernel_out & exc_mask) ----------------
__global__ __launch_bounds__(256) void out_gemm(const float* __restrict__ rmean,
                                                const int* __restrict__ ko,
                                                const u32* __restrict__ flag,
                                                float* __restrict__ dout){
  const int b = blockIdx.x;
  const int o = blockIdx.y * 256 + threadIdx.x;
  const bool bm = (*flag) != 0;
  const unsigned char* kob = (const unsigned char*)ko;
  const float* rm = rmean + (size_t)b * 4096;
  float s = 0.f;
  #pragma unroll 8
  for (int n = 0; n < 2048; ++n){
    size_t idx = (size_t)n * 512 + o;
    int kv = bm ? (int)kob[idx] : ko[idx];
    s += rm[n] * (float)kv;
  }
  dout[1048576 + (size_t)b * 512 + o] = R_OUT * s;
}

extern "C" void kernel_launch(void* const* d_in, const int* in_sizes, int n_in,
                              void* d_out, int out_size, void* d_ws, size_t ws_size,
                              hipStream_t stream){
  (void)in_sizes; (void)n_in; (void)out_size; (void)ws_size;
  const float* x   = (const float*)d_in[0];
  const float* v0  = (const float*)d_in[1];
  const float* is0 = (const float*)d_in[2];
  const float* r0  = (const float*)d_in[3];
  const int*   s0  = (const int*)d_in[4];
  const int*   kin = (const int*)d_in[5];
  const int*   kh  = (const int*)d_in[6];
  const int*   ko  = (const int*)d_in[7];
  float* out = (float*)d_out;
  char* ws = (char*)d_ws;

  // rmean overlaps xb: xb is dead after gemm_iin, rmean written by snn_scan afterwards.
  u16*  xb    = (u16*)(ws);                       // [0, 33554432)
  float* rmean= (float*)(ws);                     // [0, 1048576)  lifetime-disjoint with xb
  float* sbeta= (float*)(ws + 33554432);          // 65,536 B
  u16*  iin   = (u16*)(ws + 33619968);            // 134,217,728 B
  u16*  Bt    = (u16*)(ws + 167837696);           // 8,388,608 B
  u64*  khT   = (u64*)(ws + 176226304);           // 2,097,152 B
  u64*  khR   = (u64*)(ws + 178323456);           // 2,097,152 B
  u32*  flag  = (u32*)(ws + 180420608);           // 4 B

  hipMemsetAsync(flag, 0, 4, stream);
  detect_layout<<<dim3(1), dim3(256), 0, stream>>>((const u32*)kh, flag);
  prep_x<<<dim3(16384), dim3(256), 0, stream>>>(x, xb, sbeta);
  prep_bt<<<dim3(16, 64), dim3(256), 0, stream>>>(kin, flag, Bt);
  prep_kh<<<dim3(16, 64), dim3(256), 0, stream>>>(kh, flag, khT);
  prep_khR<<<dim3(1024), dim3(256), 0, stream>>>(kh, flag, khR);
  gemm_iin<<<dim3(128, 32), dim3(256), 0, stream>>>(xb, Bt, sbeta, iin);
  snn_scan<<<dim3(64), dim3(512), 0, stream>>>(iin, khT, khR, v0, is0, r0, s0, out, rmean);
  out_gemm<<<dim3(64, 2), dim3(256), 0, stream>>>(rmean, ko, flag, out);
}

// Round 5
// 1461.723 us; speedup vs baseline: 7.0862x; 1.0848x over previous
//
#include <hip/hip_runtime.h>

typedef unsigned short u16;
typedef unsigned int   u32;
typedef unsigned long long u64;

typedef short bf16x8 __attribute__((ext_vector_type(8)));
typedef float f32x4  __attribute__((ext_vector_type(4)));

#define A_SYN  0.90483741803595957f   // exp(-0.5/5)
#define A_VM   0.95122942450071400f   // exp(-0.5/10)
#define BETA   0.04877057549928600f   // 1 - A_VM
#define C_RATE 0.09754115099857200f   // (1/DT)*(1-alpha_out) = 2*BETA
#define R_H    0.04419417382415922f   // 1*1*10/5 * sqrt(1/2048)
#define R_IN   4.41941738241592200f   // 10*1*10 * sqrt(1/512)
#define R_OUT  2.20970869120796080f   // 100 * sqrt(1/2048)

__device__ __forceinline__ u16 f2b(float f){
  u32 x = __float_as_uint(f);
  return (u16)((x + 0x7FFFu + ((x >> 16) & 1u)) >> 16);   // RNE f32->bf16
}
__device__ __forceinline__ float b2f(u16 u){ return __uint_as_float(((u32)u) << 16); }

// ---------------- prep: row sums of x -> sbeta[m]; convert x to bf16 ----------------
__global__ __launch_bounds__(256) void prep_x(const float* __restrict__ x,
                                              u16* __restrict__ xb,
                                              float* __restrict__ sbeta){
  const int m = blockIdx.x;
  const int tid = threadIdx.x;
  const float4 xv = ((const float4*)(x + (size_t)m * 1024))[tid];
  float s = xv.x + xv.y + xv.z + xv.w;
  #pragma unroll
  for (int off = 32; off > 0; off >>= 1) s += __shfl_down(s, off, 64);
  __shared__ float ps[4];
  if ((tid & 63) == 0) ps[tid >> 6] = s;
  __syncthreads();
  float tot = ps[0] + ps[1] + ps[2] + ps[3];
  float sc = fminf(30.0f / (tot + 1.0f), 10.0f) * (R_IN * BETA);
  if (tid == 0) sbeta[m] = sc;
  ushort4 o; o.x = f2b(xv.x); o.y = f2b(xv.y); o.z = f2b(xv.z); o.w = f2b(xv.w);
  ((ushort4*)(xb + (size_t)m * 1024))[tid] = o;
}

// ---------------- detect bool layout: int32 words (0/1) vs packed bytes ----------------
__global__ void detect_layout(const u32* __restrict__ khw, u32* __restrict__ flag){
  u32 bad = 0;
  #pragma unroll
  for (int i = 0; i < 4; ++i){ u32 v = khw[threadIdx.x + i * 256]; bad |= (v > 1u) ? 1u : 0u; }
  if (bad) *flag = 1u;
}

// ---------------- prep: kernel_in -> Bt[n][k] bf16 (transposed) ----------------
__global__ __launch_bounds__(256) void prep_bt(const int* __restrict__ ki,
                                               const u32* __restrict__ flag,
                                               u16* __restrict__ Bt){
  __shared__ u16 tile[64][65];
  const int k0 = blockIdx.x * 64, n0 = blockIdx.y * 64;
  const int tr = threadIdx.x >> 6, tc = threadIdx.x & 63;
  const bool bm = (*flag) != 0;
  const unsigned char* kib = (const unsigned char*)ki;
  #pragma unroll 4
  for (int r = 0; r < 16; ++r){
    int row = r * 4 + tr;
    size_t idx = (size_t)(k0 + row) * 4096 + (n0 + tc);
    int v = bm ? (int)kib[idx] : ki[idx];
    tile[row][tc] = v ? (u16)0x3F80 : (u16)0;
  }
  __syncthreads();
  #pragma unroll 4
  for (int r = 0; r < 16; ++r){
    int row = r * 4 + tr;
    Bt[(size_t)(n0 + row) * 1024 + (k0 + tc)] = tile[tc][row];
  }
}

// ---------------- prep: kernel_h -> khT bit-packed [w][n], bit j = kh[w*64+j][n] ----------------
__global__ __launch_bounds__(256) void prep_kh(const int* __restrict__ kh,
                                               const u32* __restrict__ flag,
                                               u64* __restrict__ khT){
  const int n = blockIdx.x * 256 + threadIdx.x;
  const int w = blockIdx.y;
  const bool bm = (*flag) != 0;
  const unsigned char* khb = (const unsigned char*)kh;
  u64 bits = 0;
  #pragma unroll 8
  for (int j = 0; j < 64; ++j){
    size_t idx = (size_t)(w * 64 + j) * 4096 + n;
    int v = bm ? (int)khb[idx] : kh[idx];
    bits |= (u64)(v & 1) << j;
  }
  khT[(size_t)w * 4096 + n] = bits;
}

// ---------------- prep: kernel_h -> khR bit-packed rows [p][w], bit l = kh[p][w*64+l] ----------------
__global__ __launch_bounds__(256) void prep_khR(const int* __restrict__ kh,
                                                const u32* __restrict__ flag,
                                                u64* __restrict__ khR){
  const int p = blockIdx.x * 4 + (threadIdx.x >> 6);
  const int e = threadIdx.x & 63;
  const bool bm = (*flag) != 0;
  u64 bits = 0;
  if (bm){
    const unsigned char* src = (const unsigned char*)kh + (size_t)p * 4096 + e * 64;
    #pragma unroll 8
    for (int l = 0; l < 64; ++l) bits |= (u64)(src[l] & 1) << l;
  } else {
    const int* src = kh + (size_t)p * 4096 + e * 64;
    #pragma unroll 8
    for (int l = 0; l < 64; ++l) bits |= (u64)(src[l] & 1) << l;
  }
  khR[(size_t)p * 64 + e] = bits;
}

// ---------------- bf16 GEMM with XCD swizzle ----------------
__global__ __launch_bounds__(256) void gemm_iin(const u16* __restrict__ A,
                                                const u16* __restrict__ Bm,
                                                const float* __restrict__ sbeta,
                                                u16* __restrict__ C){
  __shared__ u16 As[128 * 32];
  __shared__ u16 Bs[128 * 32];
  const int tid = threadIdx.x;
  const int lane = tid & 63, w = tid >> 6;
  const int wm = w >> 1, wn = w & 1;
  // XCD swizzle: 4096 wgs, 8 XCDs -> XCD k owns 4 consecutive n-tiles (B-panel L2-resident)
  const int id = blockIdx.y * 128 + blockIdx.x;
  const int swz = (id & 7) * 512 + (id >> 3);
  const int m0 = (swz & 127) * 128, n0 = (swz >> 7) * 128;
  const int l15 = lane & 15, lq = lane >> 4;
  const int K = 1024;

  f32x4 acc[4][4];
  #pragma unroll
  for (int i = 0; i < 4; ++i)
    #pragma unroll
    for (int j = 0; j < 4; ++j) acc[i][j] = (f32x4){0.f, 0.f, 0.f, 0.f};

  const u16* ag = A  + (size_t)(m0 + (tid >> 2)) * K + (tid & 3) * 8;
  const u16* bg = Bm + (size_t)(n0 + (tid >> 2)) * K + (tid & 3) * 8;

  for (int kt = 0; kt < 32; ++kt){
    __builtin_amdgcn_global_load_lds((const __attribute__((address_space(1))) u32*)(ag + kt * 32),
        (__attribute__((address_space(3))) u32*)(As + tid * 8), 16, 0, 0);
    __builtin_amdgcn_global_load_lds((const __attribute__((address_space(1))) u32*)(ag + (size_t)64 * K + kt * 32),
        (__attribute__((address_space(3))) u32*)(As + 2048 + tid * 8), 16, 0, 0);
    __builtin_amdgcn_global_load_lds((const __attribute__((address_space(1))) u32*)(bg + kt * 32),
        (__attribute__((address_space(3))) u32*)(Bs + tid * 8), 16, 0, 0);
    __builtin_amdgcn_global_load_lds((const __attribute__((address_space(1))) u32*)(bg + (size_t)64 * K + kt * 32),
        (__attribute__((address_space(3))) u32*)(Bs + 2048 + tid * 8), 16, 0, 0);
    __syncthreads();
    bf16x8 af[4], bf[4];
    #pragma unroll
    for (int f = 0; f < 4; ++f){
      af[f] = *(const bf16x8*)(As + (wm * 64 + f * 16 + l15) * 32 + lq * 8);
      bf[f] = *(const bf16x8*)(Bs + (wn * 64 + f * 16 + l15) * 32 + lq * 8);
    }
    #pragma unroll
    for (int fm = 0; fm < 4; ++fm)
      #pragma unroll
      for (int fn = 0; fn < 4; ++fn)
        acc[fm][fn] = __builtin_amdgcn_mfma_f32_16x16x32_bf16(af[fm], bf[fn], acc[fm][fn], 0, 0, 0);
    __syncthreads();
  }

  float sb[4][4];
  #pragma unroll
  for (int fm = 0; fm < 4; ++fm)
    #pragma unroll
    for (int i = 0; i < 4; ++i)
      sb[fm][i] = sbeta[m0 + wm * 64 + fm * 16 + lq * 4 + i];
  #pragma unroll
  for (int fm = 0; fm < 4; ++fm)
    #pragma unroll
    for (int fn = 0; fn < 4; ++fn)
      #pragma unroll
      for (int i = 0; i < 4; ++i){
        size_t row = (size_t)(m0 + wm * 64 + fm * 16 + lq * 4 + i);
        int col = n0 + wn * 64 + fn * 16 + l15;
        C[row * 4096 + col] = f2b(acc[fm][fn][i] * sb[fm][i]);
      }
}

// ================= SNN scan: 512 threads, 8 neurons/thread (n = tid + 512j) =================
// Event protocol: per-wave segments, no LDS atomics, producer-side tag resolution.
// event u32: bits0-11 p | bit12 neg | bit13 hit | bits14-19 slot | bit20 install

struct ScanLds {
  unsigned char cntb[2][8];          // per-wave count (0xFF = overflow -> masks)
  u32 seg[2][8][4] __attribute__((aligned(16)));
  u64 fpos[2][64], fneg[2][64];      // [j*8+w] (written only on overflow)
  u32 tag[64];                       // hot-slot tags (install-only, no eviction)
};

__device__ __forceinline__ void produce(
    int lane, int w, int buf,
    const u64 (&bsp)[8], const u64 (&bfl)[8],
    ScanLds* L)
{
  if (lane == 0){
    int cnt = 0;
    #pragma unroll
    for (int j = 0; j < 8; ++j) cnt += __popcll(bfl[j]);
    u32 cb = 0;
    if (cnt > 0 && cnt <= 4){
      cb = (u32)cnt;
      int idx = 0;
      #pragma unroll 1
      for (int j = 0; j < 8; ++j){
        u64 m = bfl[j];
        while (m){
          int bit = (int)__builtin_ctzll(m); m &= m - 1;
          u32 p = (u32)(j * 512 + w * 64 + bit);
          u32 rising = (u32)((bsp[j] >> bit) & 1ull);
          u32 neg = (j < 4) ? (rising ^ 1u) : rising;     // dale sign (exc iff p<2048)
          u32 s = (p ^ (p >> 6)) & 63u;
          u32 tg = L->tag[s];
          u32 ev = p | (neg << 12) | (s << 14);
          if (tg == p) ev |= (1u << 13);                  // hit
          else if (tg == 0xFFFFFFFFu) ev |= (1u << 20);   // miss -> install
          L->seg[buf][w][idx++] = ev;
        }
      }
    } else if (cnt > 4){
      cb = 0xFFu;
      #pragma unroll
      for (int j = 0; j < 8; ++j){
        L->fpos[buf][j * 8 + w] = bfl[j] & bsp[j];
        L->fneg[buf][j * 8 + w] = bfl[j] & ~bsp[j];
      }
    }
    L->cntb[buf][w] = (unsigned char)cb;
  }
}

__device__ __forceinline__ void apply_ev(
    u32 ev, int tid, int lane, int w,
    const u64* __restrict__ khR,
    ScanLds* L, int (&acc)[8], u64 (&hotbits)[8])
{
  u32 p = ev & 4095u;
  u32 s = (ev >> 14) & 63u;
  int sg = (ev & (1u << 12)) ? -1 : 1;
  if (ev & (1u << 13)){                       // hit: pure VALU
    #pragma unroll
    for (int j = 0; j < 8; ++j)
      acc[j] += sg * (int)((hotbits[j] >> s) & 1ull);
  } else {
    const u64* rp = khR + ((size_t)p << 6) + w;
    if (ev & (1u << 20)){                     // miss + install
      u64 sm = 1ull << s;
      #pragma unroll
      for (int j = 0; j < 8; ++j){
        u64 r = rp[8 * j];
        u64 bit = (r >> lane) & 1ull;
        acc[j] += sg * (int)bit;
        hotbits[j] = (hotbits[j] & ~sm) | (bit << s);
      }
      if (tid == 0) L->tag[s] = p;
    } else {                                  // miss (collision): no install
      #pragma unroll
      for (int j = 0; j < 8; ++j)
        acc[j] += sg * (int)((rp[8 * j] >> lane) & 1ull);
    }
  }
}

__device__ __forceinline__ void consume(
    int tid, int lane, int w, int buf,
    const u64* __restrict__ khT, const u64* __restrict__ khR,
    ScanLds* L, int (&acc)[8], float (&racc)[8], u64 (&hotbits)[8])
{
  u64 cw = *(const u64*)&L->cntb[buf][0];     // one uniform b64 broadcast load
  if (cw == 0ull) return;
  if (cw & 0x8080808080808080ull){
    // mixed/dense (t=0 onset): overflow waves via khT masks, others via segments
    #pragma unroll 1
    for (int ww = 0; ww < 8; ++ww){
      u32 c = (u32)((cw >> (8 * ww)) & 0xFFull);
      if (!c) continue;
      if (c == 0xFFu){
        #pragma unroll 1
        for (int j = 0; j < 8; ++j){
          int w2 = j * 8 + ww;
          u64 fp = L->fpos[buf][w2], fn = L->fneg[buf][w2];
          if (!(fp | fn)) continue;
          const u64* kp = khT + ((size_t)w2 << 12) + tid;
          #pragma unroll
          for (int jj = 0; jj < 8; ++jj){
            u64 k = kp[512 * jj];
            int tt = __popcll(fp & k) - __popcll(fn & k);
            acc[jj] += (w2 < 32) ? tt : -tt;
          }
        }
      } else {
        uint4 q = *(const uint4*)&L->seg[buf][ww][0];
        u32 evs[4] = {q.x, q.y, q.z, q.w};
        #pragma unroll
        for (int i = 0; i < 4; ++i)
          if ((u32)i < c) apply_ev(evs[i], tid, lane, w, khR, L, acc, hotbits);
      }
    }
  } else {
    #pragma unroll 1
    for (int ww = 0; ww < 8; ++ww){
      u32 c = (u32)((cw >> (8 * ww)) & 0xFFull);
      if (!c) continue;
      uint4 q = *(const uint4*)&L->seg[buf][ww][0];
      u32 evs[4] = {q.x, q.y, q.z, q.w};
      #pragma unroll
      for (int i = 0; i < 4; ++i)
        if ((u32)i < c) apply_ev(evs[i], tid, lane, w, khR, L, acc, hotbits);
    }
  }
  #pragma unroll
  for (int j = 0; j < 8; ++j) racc[j] = R_H * (float)acc[j];
}

__device__ __forceinline__ void snn_step(
    int t, int tid, int lane, int w, const u16* __restrict__ ip,
    const u64* __restrict__ khT, const u64* __restrict__ khR,
    u16 (&cur)[8],
    float (&v)[8], float (&isy)[8], float (&rate)[8], float (&rsum)[8],
    float (&racc)[8], int (&acc)[8], bool (&prev)[8], u64 (&hotbits)[8],
    ScanLds* L)
{
  const int buf = t & 1;
  bool sn[8];
  #pragma unroll
  for (int j = 0; j < 8; ++j){
    isy[j] = fmaf(isy[j], A_SYN, racc[j]);
    float tv = fmaf(isy[j], BETA, b2f(cur[j]));   // beta*i_syn + beta*R_in*scale*(x@Kin)
    float vv = fmaf(v[j], A_VM, tv);
    sn[j] = vv > 1.0f;
    v[j] = sn[j] ? 0.0f : vv;
    rate[j] = fmaf(rate[j], A_VM, sn[j] ? C_RATE : 0.0f);  // alpha_out == alpha_vm
    rsum[j] += rate[j];
  }
  u64 bsp[8], bfl[8];
  #pragma unroll
  for (int j = 0; j < 8; ++j){
    bsp[j] = __ballot(sn[j]);
    bfl[j] = __ballot(sn[j] != prev[j]);
    prev[j] = sn[j];
  }
  produce(lane, w, buf, bsp, bfl, L);
  __syncthreads();
  // refill for t+2 AFTER the barrier: the vmcnt(0) drain at the NEXT barrier
  // has a full step of slack -> HBM latency hidden (not serialized per step).
  if (t + 2 < 256){
    const u16* q = ip + (size_t)(t + 2) * 4096;
    #pragma unroll
    for (int j = 0; j < 8; ++j) cur[j] = q[j * 512];
  }
  consume(tid, lane, w, buf, khT, khR, L, acc, racc, hotbits);
}

__global__ __launch_bounds__(512, 2) void snn_scan(
    const u16* __restrict__ iin, const u64* __restrict__ khT,
    const u64* __restrict__ khR,
    const float* __restrict__ v0, const float* __restrict__ is0,
    const float* __restrict__ r0, const int* __restrict__ s0,
    float* __restrict__ dout, float* __restrict__ rmean)
{
  const int b = blockIdx.x, tid = threadIdx.x;
  const int lane = tid & 63, w = tid >> 6;     // 8 waves
  __shared__ ScanLds L;

  if (tid < 64) L.tag[tid] = 0xFFFFFFFFu;

  float v[8], isy[8], rate[8], rsum[8], racc[8];
  int acc[8]; bool prev[8]; u64 hotbits[8];
  const size_t base = (size_t)b * 4096 + tid;
  const unsigned char* s0b = (const unsigned char*)s0;   // spike0 all-zero; byte-safe either layout
  #pragma unroll
  for (int j = 0; j < 8; ++j){
    v[j]    = v0 [base + j * 512];
    isy[j]  = is0[base + j * 512];
    rate[j] = r0 [base + j * 512];
    rsum[j] = 0.f;
    prev[j] = s0b[base + j * 512] != 0;
    acc[j] = 0; racc[j] = 0.f; hotbits[j] = 0ull;
  }
  __syncthreads();   // tag initialized before first produce reads it

  { // init event (t=-1, buf=1): flips = spike0 rising
    u64 bsp[8], bfl[8];
    #pragma unroll
    for (int j = 0; j < 8; ++j){ bsp[j] = __ballot(prev[j]); bfl[j] = bsp[j]; }
    produce(lane, w, 1, bsp, bfl, &L);
    __syncthreads();
    consume(tid, lane, w, 1, khT, khR, &L, acc, racc, hotbits);
  }

  const u16* ip = iin + (size_t)b * 256 * 4096 + tid;
  u16 bufA[8], bufB[8];
  #pragma unroll
  for (int j = 0; j < 8; ++j) bufA[j] = ip[j * 512];
  #pragma unroll
  for (int j = 0; j < 8; ++j) bufB[j] = ip[4096 + j * 512];

  for (int t = 0; t < 256; t += 2){
    snn_step(t,     tid, lane, w, ip, khT, khR, bufA,
             v, isy, rate, rsum, racc, acc, prev, hotbits, &L);
    snn_step(t + 1, tid, lane, w, ip, khT, khR, bufB,
             v, isy, rate, rsum, racc, acc, prev, hotbits, &L);
  }

  #pragma unroll
  for (int j = 0; j < 8; ++j){
    size_t o = base + (size_t)j * 512;
    dout[o]           = v[j];
    dout[262144 + o]  = isy[j];
    dout[524288 + o]  = rate[j];
    dout[786432 + o]  = prev[j] ? 1.0f : 0.0f;
    rmean[o] = rsum[j] * 0.00390625f;
  }
}

// ---------------- output head: R_out * rate_mean @ (kernel_out & exc_mask) ----------------
__global__ __launch_bounds__(256) void out_gemm(const float* __restrict__ rmean,
                                                const int* __restrict__ ko,
                                                const u32* __restrict__ flag,
                                                float* __restrict__ dout){
  const int b = blockIdx.x;
  const int o = blockIdx.y * 256 + threadIdx.x;
  const bool bm = (*flag) != 0;
  const unsigned char* kob = (const unsigned char*)ko;
  const float* rm = rmean + (size_t)b * 4096;
  float s = 0.f;
  #pragma unroll 8
  for (int n = 0; n < 2048; ++n){
    size_t idx = (size_t)n * 512 + o;
    int kv = bm ? (int)kob[idx] : ko[idx];
    s += rm[n] * (float)kv;
  }
  dout[1048576 + (size_t)b * 512 + o] = R_OUT * s;
}

extern "C" void kernel_launch(void* const* d_in, const int* in_sizes, int n_in,
                              void* d_out, int out_size, void* d_ws, size_t ws_size,
                              hipStream_t stream){
  (void)in_sizes; (void)n_in; (void)out_size; (void)ws_size;
  const float* x   = (const float*)d_in[0];
  const float* v0  = (const float*)d_in[1];
  const float* is0 = (const float*)d_in[2];
  const float* r0  = (const float*)d_in[3];
  const int*   s0  = (const int*)d_in[4];
  const int*   kin = (const int*)d_in[5];
  const int*   kh  = (const int*)d_in[6];
  const int*   ko  = (const int*)d_in[7];
  float* out = (float*)d_out;
  char* ws = (char*)d_ws;

  // rmean overlaps xb: xb is dead after gemm_iin, rmean written by snn_scan afterwards.
  u16*  xb    = (u16*)(ws);                       // [0, 33554432)
  float* rmean= (float*)(ws);                     // [0, 1048576)  lifetime-disjoint with xb
  float* sbeta= (float*)(ws + 33554432);          // 65,536 B
  u16*  iin   = (u16*)(ws + 33619968);            // 134,217,728 B
  u16*  Bt    = (u16*)(ws + 167837696);           // 8,388,608 B
  u64*  khT   = (u64*)(ws + 176226304);           // 2,097,152 B
  u64*  khR   = (u64*)(ws + 178323456);           // 2,097,152 B
  u32*  flag  = (u32*)(ws + 180420608);           // 4 B

  hipMemsetAsync(flag, 0, 4, stream);
  detect_layout<<<dim3(1), dim3(256), 0, stream>>>((const u32*)kh, flag);
  prep_x<<<dim3(16384), dim3(256), 0, stream>>>(x, xb, sbeta);
  prep_bt<<<dim3(16, 64), dim3(256), 0, stream>>>(kin, flag, Bt);
  prep_kh<<<dim3(16, 64), dim3(256), 0, stream>>>(kh, flag, khT);
  prep_khR<<<dim3(1024), dim3(256), 0, stream>>>(kh, flag, khR);
  gemm_iin<<<dim3(128, 32), dim3(256), 0, stream>>>(xb, Bt, sbeta, iin);
  snn_scan<<<dim3(64), dim3(512), 0, stream>>>(iin, khT, khR, v0, is0, r0, s0, out, rmean);
  out_gemm<<<dim3(64, 2), dim3(256), 0, stream>>>(rmean, ko, flag, out);
}